// Round 13
// baseline (1502.219 us; speedup 1.0000x reference)
//
#include <hip/hip_runtime.h>
#include <hip/hip_bf16.h>

#define DDIM 1024
#define HDIM 4096
#define NEXP 8
#define NROW 8192
#define KPAIR 8192   // 2 experts * HDIM

typedef __attribute__((ext_vector_type(8))) short s16x8;
typedef __attribute__((ext_vector_type(4))) float f32x4;

using bf16 = __hip_bfloat16;

// ---------------------------------------------------------------- helpers
__device__ __forceinline__ void gload16(const bf16* g, bf16* lds) {
    __builtin_amdgcn_global_load_lds(
        (const __attribute__((address_space(1))) unsigned int*)g,
        (__attribute__((address_space(3))) unsigned int*)lds,
        16, 0, 0);
}

template <int N>
__device__ __forceinline__ void wait_vmcnt() {
    if constexpr (N == 6)      asm volatile("s_waitcnt vmcnt(6)" ::: "memory");
    else if constexpr (N == 3) asm volatile("s_waitcnt vmcnt(3)" ::: "memory");
    else                       asm volatile("s_waitcnt vmcnt(0)" ::: "memory");
}

// ---------------------------------------- fused x->bf16 convert + gate softmax
__global__ void cvtgate_kernel(const float* __restrict__ x, const float* __restrict__ Wg,
                               const float* __restrict__ bg, bf16* __restrict__ xb,
                               float* __restrict__ wts) {
    int wave = threadIdx.x >> 6, lane = threadIdx.x & 63;
    int n = blockIdx.x * 4 + wave;
    const float* xr = x + (size_t)n * DDIM;
    bf16* xbr = xb + (size_t)n * DDIM;
    float acc[NEXP] = {0.f, 0.f, 0.f, 0.f, 0.f, 0.f, 0.f, 0.f};
#pragma unroll
    for (int j = 0; j < 4; ++j) {
        int d0 = j * 256 + lane * 4;
        float4 v = *(const float4*)&xr[d0];
        union { bf16 b[4]; uint2 u; } pk;
        pk.b[0] = __float2bfloat16(v.x);
        pk.b[1] = __float2bfloat16(v.y);
        pk.b[2] = __float2bfloat16(v.z);
        pk.b[3] = __float2bfloat16(v.w);
        *(uint2*)&xbr[d0] = pk.u;
        const float* w0 = Wg + (size_t)d0 * NEXP;
#pragma unroll
        for (int e = 0; e < NEXP; ++e)
            acc[e] += v.x * w0[e] + v.y * w0[NEXP + e] + v.z * w0[2 * NEXP + e] +
                      v.w * w0[3 * NEXP + e];
    }
#pragma unroll
    for (int off = 32; off > 0; off >>= 1) {
#pragma unroll
        for (int e = 0; e < NEXP; ++e) acc[e] += __shfl_xor(acc[e], off, 64);
    }
    if (lane == 0) {
        float mx = -1e30f;
#pragma unroll
        for (int e = 0; e < NEXP; ++e) { acc[e] += bg[e]; mx = fmaxf(mx, acc[e]); }
        float s = 0.f;
#pragma unroll
        for (int e = 0; e < NEXP; ++e) { acc[e] = __expf(acc[e] - mx); s += acc[e]; }
        float inv = 1.0f / s;
#pragma unroll
        for (int e = 0; e < NEXP; ++e) wts[(size_t)n * NEXP + e] = acc[e] * inv;
    }
}

// ------------------ fp32 src [R][C] (+z*szs) -> bf16 dst [C][ldo] (+z*dzo)
__global__ void transpose_cvt_kernel(const float* __restrict__ src, bf16* __restrict__ dst,
                                     int R, int C, int ldo, size_t szs, int dzo) {
    __shared__ float t[128][65];
    const float* s = src + (size_t)blockIdx.z * szs;
    bf16* d = dst + (size_t)blockIdx.z * dzo;
    const int r0 = blockIdx.y * 64, c0 = blockIdx.x * 128;
    const int tid = threadIdx.x;
    const int lrow = tid >> 5, lc4 = tid & 31;
#pragma unroll
    for (int i = 0; i < 8; ++i) {
        int rr = i * 8 + lrow;
        float4 v = *(const float4*)&s[(size_t)(r0 + rr) * C + c0 + lc4 * 4];
        t[lc4 * 4 + 0][rr] = v.x;
        t[lc4 * 4 + 1][rr] = v.y;
        t[lc4 * 4 + 2][rr] = v.z;
        t[lc4 * 4 + 3][rr] = v.w;
    }
    __syncthreads();
    const int oc = tid >> 3, oj = tid & 7;
#pragma unroll
    for (int i = 0; i < 4; ++i) {
        int c = oc + i * 32;
        union { bf16 b[8]; s16x8 v; } p;
#pragma unroll
        for (int q = 0; q < 8; ++q) p.b[q] = __float2bfloat16(t[c][oj * 8 + q]);
        *(s16x8*)&d[(size_t)(c0 + c) * ldo + r0 + oj * 8] = p.v;
    }
}

// ------------------------------------------- out[n,d] = sum_e w[n,e]*b2[e,d]
__global__ void out_init_kernel(const float* __restrict__ wts, const float* __restrict__ b2,
                                float* __restrict__ out) {
    size_t idx = (size_t)blockIdx.x * 256 + threadIdx.x;
    int d = (int)(idx & (DDIM - 1));
    size_t n = idx >> 10;
    const float* w = wts + n * NEXP;
    float s = 0.f;
#pragma unroll
    for (int e = 0; e < NEXP; ++e) s += w[e] * b2[(size_t)e * DDIM + d];
    out[idx] = s;
}

// ---------------------------------------------------------------- GEMM1 (8-phase, BK=64)
// BM=256 x BN=256, 8 waves 2(M)x4(N), wave-tile 128x64. PAIR-FUSED dispatch
// (grid 1024; round-11 structure = best replay-measured G1). Epilogue:
// Hs = wts[row,e]*relu(acc+b1), LDS-buffered coalesced store with granule-XOR
// swizzle (cl ^ ((rl&7)<<3)): 4-way bank alias -> 2-way (free).
__global__ __launch_bounds__(512, 1) void gemm1(
    const bf16* __restrict__ A, const bf16* __restrict__ BTp, bf16* __restrict__ Hsb,
    const float* __restrict__ b1p, const float* __restrict__ wts,
    int lda, int ldb, int ldc, int NT, int tilesM, int tilesN, int XGN, int e0) {
    constexpr int WROWS = 128;
    constexpr int HALFA = 256 * 32;
    constexpr int HALFB = 256 * 32;
    constexpr int ATOT = 2 * HALFA;
    constexpr int BUFE = ATOT + 2 * HALFB;  // 32768 elems
    __shared__ __align__(16) bf16 smem[2 * BUFE];

    const int tid = threadIdx.x;
    const int wave = tid >> 6, lane = tid & 63;
    const int wm = wave >> 2, wn = wave & 3;
    const int r = lane & 15, kg = lane >> 4;

    // expert half of the pair
    const int eh = blockIdx.x >> 9;
    const int bx = blockIdx.x & 511;
    const bf16* BT = BTp + (size_t)eh * HDIM * DDIM;
    bf16* Cout = Hsb + (size_t)eh * HDIM;
    const float* bias = b1p + (size_t)eh * HDIM;
    const int expert = e0 + eh;

    // ---- 2-D XCD-aware tile mapping (round-3 FETCH-verified)
    const int xcd = bx & 7, slot = bx >> 3;
    const int XGM = 8 / XGN;
    const int rm = tilesM / XGM, rn = tilesN / XGN;
    const int g = slot >> 5, u = slot & 31;
    const int gpr = rn >> 3;
    const int gm = (g / gpr) * 4 + (u >> 3);
    const int gn = (g % gpr) * 8 + (u & 7);
    const int tm = (xcd / XGN) * rm + gm;
    const int tn = (xcd % XGN) * rn + gn;

    const bf16* gA = A + (size_t)tm * 256 * lda;
    const bf16* gB = BT + (size_t)tn * 256 * ldb;

    f32x4 acc[8][4];
#pragma unroll
    for (int m = 0; m < 8; ++m)
#pragma unroll
        for (int n = 0; n < 4; ++n) acc[m][n] = (f32x4){0.f, 0.f, 0.f, 0.f};

    auto stageA = [&](int t, int ks) {
        bf16* dst = smem + (t & 1) * BUFE + ks * HALFA;
#pragma unroll
        for (int j = 0; j < 2; ++j) {
            int c = j * 512 + tid;
            int R = c >> 2, kc = (c & 3) ^ ((R >> 1) & 3);
            gload16(gA + (size_t)R * lda + t * 64 + ks * 32 + kc * 8,
                    dst + (j * 512 + wave * 64) * 8);
        }
    };
    auto stageB = [&](int t, int ks) {
        bf16* dst = smem + (t & 1) * BUFE + ATOT + ks * HALFB;
#pragma unroll
        for (int j = 0; j < 2; ++j) {
            int c = j * 512 + tid;
            int R = c >> 2, kc = (c & 3) ^ ((R >> 1) & 3);
            gload16(gB + (size_t)R * ldb + t * 64 + ks * 32 + kc * 8,
                    dst + (j * 512 + wave * 64) * 8);
        }
    };

    s16x8 a0[4], bb[4];
    auto ldA = [&](int buf, int ks, int mh) {
#pragma unroll
        for (int m = 0; m < 4; ++m) {
            int R = wm * WROWS + mh * 64 + m * 16 + r;
            a0[m] = *(const s16x8*)&smem[buf * BUFE + ks * HALFA + R * 32 +
                                         ((kg ^ ((R >> 1) & 3)) * 8)];
        }
    };
    auto ldB = [&](int buf, int ks) {
#pragma unroll
        for (int n = 0; n < 4; ++n) {
            int R = wn * 64 + n * 16 + r;
            bb[n] = *(const s16x8*)&smem[buf * BUFE + ATOT + ks * HALFB + R * 32 +
                                         ((kg ^ ((R >> 1) & 3)) * 8)];
        }
    };

    auto preMFMA = [&]() {
        __builtin_amdgcn_s_barrier();
        asm volatile("s_waitcnt lgkmcnt(0)" ::: "memory");
        __builtin_amdgcn_sched_barrier(0);
        __builtin_amdgcn_s_setprio(1);
    };
    auto postMFMA = [&](bool vm) {
        __builtin_amdgcn_s_setprio(0);
        if (vm) wait_vmcnt<6>();
        __builtin_amdgcn_s_barrier();
    };
    auto mfmaLo = [&]() {
#pragma unroll
        for (int m = 0; m < 4; ++m)
#pragma unroll
            for (int n = 0; n < 4; ++n)
                acc[m][n] = __builtin_amdgcn_mfma_f32_16x16x32_bf16(a0[m], bb[n], acc[m][n], 0, 0, 0);
    };
    auto mfmaHi = [&]() {
#pragma unroll
        for (int m = 0; m < 4; ++m)
#pragma unroll
            for (int n = 0; n < 4; ++n)
                acc[4 + m][n] = __builtin_amdgcn_mfma_f32_16x16x32_bf16(a0[m], bb[n], acc[4 + m][n], 0, 0, 0);
    };

    // prologue
    stageB(0, 0); stageA(0, 0); stageB(0, 1); stageA(0, 1);
    stageB(1, 0); stageA(1, 0); stageB(1, 1);   // A(1,1) staged at iter0 ph1
    wait_vmcnt<6>();
    __builtin_amdgcn_s_barrier();

    const int NI = NT / 2;
    for (int i = 0; i < NI; ++i) {
        const int t0 = 2 * i, t1 = t0 + 1;
        const bool g2 = (t0 + 2 < NT), g3 = (t1 + 2 < NT);
        ldB(0, 0); ldA(0, 0, 0); stageA(t1, 1);
        preMFMA(); mfmaLo(); postMFMA(false);
        ldA(0, 0, 1); if (g2) stageB(t0 + 2, 0);
        preMFMA(); mfmaHi(); postMFMA(false);
        ldB(0, 1); ldA(0, 1, 0); if (g2) stageA(t0 + 2, 0);
        preMFMA(); mfmaLo(); postMFMA(false);
        ldA(0, 1, 1); if (g2) stageB(t0 + 2, 1);
        preMFMA(); mfmaHi(); postMFMA(true);
        ldB(1, 0); ldA(1, 0, 0); if (g2) stageA(t0 + 2, 1);
        preMFMA(); mfmaLo(); postMFMA(false);
        ldA(1, 0, 1); if (g3) stageB(t1 + 2, 0);
        preMFMA(); mfmaHi(); postMFMA(false);
        ldB(1, 1); ldA(1, 1, 0); if (g3) stageA(t1 + 2, 0);
        preMFMA(); mfmaLo(); postMFMA(false);
        ldA(1, 1, 1); if (g3) stageB(t1 + 2, 1);
        preMFMA(); mfmaHi(); postMFMA(true);
    }

    // ---- epilogue: Hs = w * relu(acc + bias), LDS-buffered coalesced store.
    // Granule-XOR swizzle (bijective per row): 4-way alias -> 2-way (free).
    bf16* hs = smem;                         // 65536 elems == 256*256
    const int col0 = tn * 256 + wn * 64;
#pragma unroll
    for (int n = 0; n < 4; ++n) {
        float bv = bias[col0 + n * 16 + r];
        int cl = wn * 64 + n * 16 + r;
#pragma unroll
        for (int mf = 0; mf < 8; ++mf) {
#pragma unroll
            for (int j = 0; j < 4; ++j) {
                int rl = wm * WROWS + (mf >> 2) * 64 + (mf & 3) * 16 + kg * 4 + j;
                float wv = wts[((size_t)tm * 256 + rl) * NEXP + expert];
                float v = acc[mf][n][j] + bv;
                v = v > 0.f ? v : 0.f;
                hs[rl * 256 + (cl ^ ((rl & 7) << 3))] = __float2bfloat16(wv * v);
            }
        }
    }
    __builtin_amdgcn_s_barrier();
    asm volatile("s_waitcnt lgkmcnt(0)" ::: "memory");
    const size_t rbase = (size_t)tm * 256;
    const int cbase = tn * 256;
#pragma unroll
    for (int i2 = 0; i2 < 16; ++i2) {
        int rl = wave * 32 + i2 * 2 + (lane >> 5);
        int c8 = (lane & 31) * 8;
        s16x8 v = *(const s16x8*)&hs[rl * 256 + (c8 ^ ((rl & 7) << 3))];
        *(s16x8*)&Cout[(rbase + rl) * (size_t)ldc + cbase + c8] = v;
    }
}

// ---------------------------------------------------------------- GEMM2 (expert-pair, K=8192)
// Round-10 loop (best measured): BM=256 x BN=128, BK=64, ring-3 LDS,
// 8 waves = 2(M)x2(N)x2(Ksw), one barrier per K-tile, counted lgkm/vmcnt.
// ROUND-13: epilogue split — each ksw half dumps its complementary row-half
// to LDS and RMWs 64 rows (was: ksw0 did all 128; halves the serial tail).
__global__ __launch_bounds__(512, 1) void gemm2pair(
    const bf16* __restrict__ A, const bf16* __restrict__ BT, float* __restrict__ O,
    int lda, int ldb, int ldc, int NT, int tilesM, int tilesN, int XGN) {
    constexpr int HALFA = 256 * 32;          // 8192 elems
    constexpr int HALFB = 128 * 32;          // 4096 elems
    constexpr int ATOT = 2 * HALFA;
    constexpr int BUFE = ATOT + 2 * HALFB;   // 24576 elems
    constexpr int RSTR = 68;                 // padded reduce stride (f32)
    __shared__ __align__(16) bf16 smem[3 * BUFE];   // 144 KiB

    const int tid = threadIdx.x;
    const int wave = tid >> 6, lane = tid & 63;
    const int ksw = wave & 1, wn = (wave >> 1) & 1, wm = wave >> 2;
    const int r = lane & 15, kg = lane >> 4;

    // ---- 2-D XCD-aware tile mapping (round-3 FETCH-verified)
    const int xcd = blockIdx.x & 7, slot = blockIdx.x >> 3;
    const int XGM = 8 / XGN;
    const int rm = tilesM / XGM, rn = tilesN / XGN;
    const int g = slot >> 5, u = slot & 31;
    const int gpr = rn >> 3;
    const int gm = (g / gpr) * 4 + (u >> 3);
    const int gn = (g % gpr) * 8 + (u & 7);
    const int tm = (xcd / XGN) * rm + gm;
    const int tn = (xcd % XGN) * rn + gn;

    const bf16* gA = A + (size_t)tm * 256 * lda;
    const bf16* gB = BT + (size_t)tn * 128 * ldb;

    f32x4 acc[8][4];
#pragma unroll
    for (int m = 0; m < 8; ++m)
#pragma unroll
        for (int n = 0; n < 4; ++n) acc[m][n] = (f32x4){0.f, 0.f, 0.f, 0.f};

    auto stageA = [&](int t, int ks) {
        bf16* dst = smem + (t % 3) * BUFE + ks * HALFA;
#pragma unroll
        for (int j = 0; j < 2; ++j) {
            int c = j * 512 + tid;
            int R = c >> 2, kc = (c & 3) ^ ((R >> 1) & 3);
            gload16(gA + (size_t)R * lda + t * 64 + ks * 32 + kc * 8,
                    dst + (j * 512 + wave * 64) * 8);
        }
    };
    auto stageB = [&](int t, int ks) {
        bf16* dst = smem + (t % 3) * BUFE + ATOT + ks * HALFB;
        int R = tid >> 2, kc = (tid & 3) ^ ((R >> 1) & 3);
        gload16(gB + (size_t)R * ldb + t * 64 + ks * 32 + kc * 8, dst + (wave * 64) * 8);
    };

    s16x8 a0[4], a1[4], bfr[4];
    auto ldA0 = [&](int rb) {
#pragma unroll
        for (int m = 0; m < 4; ++m) {
            int R = wm * 128 + m * 16 + r;
            a0[m] = *(const s16x8*)&smem[rb * BUFE + ksw * HALFA + R * 32 +
                                         ((kg ^ ((R >> 1) & 3)) * 8)];
        }
    };
    auto ldA1 = [&](int rb) {
#pragma unroll
        for (int m = 0; m < 4; ++m) {
            int R = wm * 128 + 64 + m * 16 + r;
            a1[m] = *(const s16x8*)&smem[rb * BUFE + ksw * HALFA + R * 32 +
                                         ((kg ^ ((R >> 1) & 3)) * 8)];
        }
    };
    auto ldB = [&](int rb) {
#pragma unroll
        for (int n = 0; n < 4; ++n) {
            int R = wn * 64 + n * 16 + r;
            bfr[n] = *(const s16x8*)&smem[rb * BUFE + ATOT + ksw * HALFB + R * 32 +
                                          ((kg ^ ((R >> 1) & 3)) * 8)];
        }
    };

    // prologue: stage tiles 0,1 (6 insts each)
    stageA(0, 0); stageB(0, 0); stageA(0, 1); stageB(0, 1);
    stageA(1, 0); stageB(1, 0); stageA(1, 1); stageB(1, 1);
    wait_vmcnt<6>();                        // tile 0 resident; tile 1 in flight
    __builtin_amdgcn_s_barrier();

    for (int t = 0; t < NT; ++t) {
        const int rb = t % 3;
        const bool gg = (t + 2 < NT);
        ldB(rb); ldA0(rb);
        if (gg) { stageA(t + 2, 0); stageB(t + 2, 0); }
        ldA1(rb);
        if (gg) { stageA(t + 2, 1); stageB(t + 2, 1); }
        asm volatile("s_waitcnt lgkmcnt(4)" ::: "memory");
        __builtin_amdgcn_sched_barrier(0);
        __builtin_amdgcn_s_setprio(1);
#pragma unroll
        for (int m = 0; m < 4; ++m)
#pragma unroll
            for (int n = 0; n < 4; ++n)
                acc[m][n] = __builtin_amdgcn_mfma_f32_16x16x32_bf16(a0[m], bfr[n], acc[m][n], 0, 0, 0);
        __builtin_amdgcn_s_setprio(0);
        asm volatile("s_waitcnt lgkmcnt(0)" ::: "memory");
        __builtin_amdgcn_sched_barrier(0);
        __builtin_amdgcn_s_setprio(1);
#pragma unroll
        for (int m = 0; m < 4; ++m)
#pragma unroll
            for (int n = 0; n < 4; ++n)
                acc[4 + m][n] = __builtin_amdgcn_mfma_f32_16x16x32_bf16(a1[m], bfr[n], acc[4 + m][n], 0, 0, 0);
        __builtin_amdgcn_s_setprio(0);
        if (t + 1 < NT) {
            if (gg) wait_vmcnt<6>();
            else    wait_vmcnt<0>();
            __builtin_amdgcn_s_barrier();
        }
    }

    // ---- split cross-ksw reduce: ksw1 dumps rows 0-63, ksw0 dumps rows
    // 64-127; each wave then RMWs the half it kept in registers.
    // 8 zones x 64 x RSTR f32 = 139 KB (fits 144 KiB smem). stride-68: 2-way.
    __syncthreads();                         // ring buffers dead
    float* red = (float*)smem;
    const int zb0 = ((wm * 2 + wn) * 2 + 0) * (64 * RSTR);   // rows 0-63
    const int zb1 = ((wm * 2 + wn) * 2 + 1) * (64 * RSTR);   // rows 64-127
    {
        // dump the half this wave will NOT write to global
        const int mfbase = (ksw == 1) ? 0 : 4;   // ksw1 dumps lo, ksw0 dumps hi
        const int zb = (ksw == 1) ? zb0 : zb1;
#pragma unroll
        for (int mq = 0; mq < 4; ++mq) {
            int mf = mfbase + mq;
#pragma unroll
            for (int n = 0; n < 4; ++n) {
                int rl = mq * 16 + kg * 4;
                int cl = n * 16 + r;
#pragma unroll
                for (int j = 0; j < 4; ++j)
                    red[zb + (rl + j) * RSTR + cl] = acc[mf][n][j];
            }
        }
    }
    __syncthreads();
    {
        // RMW the half this wave kept: ksw0 -> rows 0-63 (acc mf 0-3 + zb0),
        // ksw1 -> rows 64-127 (acc mf 4-7 + zb1).
        const int mfbase = (ksw == 0) ? 0 : 4;
        const int zb = (ksw == 0) ? zb0 : zb1;
        const size_t row0 = (size_t)tm * 256 + wm * 128 + (ksw == 0 ? 0 : 64);
        const int col0 = tn * 128 + wn * 64;
#pragma unroll
        for (int mq = 0; mq < 4; ++mq) {
            int mf = mfbase + mq;
#pragma unroll
            for (int j = 0; j < 4; ++j) {
                int rl = mq * 16 + kg * 4 + j;
                size_t rr = row0 + rl;
#pragma unroll
                for (int n = 0; n < 4; ++n) {
                    int cl = n * 16 + r;
                    float v = acc[mf][n][j] + red[zb + rl * RSTR + cl];
                    O[rr * (size_t)ldc + col0 + cl] += v;
                }
            }
        }
    }
}

// ---------------------------------------------------------------- launch
extern "C" void kernel_launch(void* const* d_in, const int* in_sizes, int n_in,
                              void* d_out, int out_size, void* d_ws, size_t ws_size,
                              hipStream_t stream) {
    const float* x  = (const float*)d_in[0];
    const float* Wg = (const float*)d_in[1];
    const float* bg = (const float*)d_in[2];
    const float* W1 = (const float*)d_in[3];
    const float* b1 = (const float*)d_in[4];
    const float* W2 = (const float*)d_in[5];
    const float* b2 = (const float*)d_in[6];
    float* out = (float*)d_out;

    char* ws = (char*)d_ws;
    bf16* xb   = (bf16*)(ws);                          // 16 MiB  [N][D]
    bf16* W1P  = (bf16*)(ws + (16ull << 20));          // 16 MiB  [2][H][D] (pair)
    bf16* W2P  = (bf16*)(ws + (32ull << 20));          // 16 MiB  [D][KPAIR] (pair)
    bf16* Hs   = (bf16*)(ws + (48ull << 20));          // 128 MiB [N][KPAIR] (pair)
    float* wts = (float*)(ws + (176ull << 20));        // 256 KiB [N][E]

    cvtgate_kernel<<<NROW / 4, 256, 0, stream>>>(x, Wg, bg, xb, wts);
    out_init_kernel<<<NROW * DDIM / 256, 256, 0, stream>>>(wts, b2, out);

    for (int p = 0; p < 4; ++p) {
        // W1 pair: [2][D][H] -> W1P [2][H][D]
        transpose_cvt_kernel<<<dim3(HDIM / 128, DDIM / 64, 2), 256, 0, stream>>>(
            W1 + (size_t)2 * p * DDIM * HDIM, W1P, DDIM, HDIM, DDIM,
            (size_t)DDIM * HDIM, HDIM * DDIM);
        // W2 pair: [2][H][D] -> W2P [D][KPAIR] (before G1 so writeback drains)
        transpose_cvt_kernel<<<dim3(DDIM / 128, HDIM / 64, 2), 256, 0, stream>>>(
            W2 + (size_t)2 * p * HDIM * DDIM, W2P, HDIM, DDIM, KPAIR,
            (size_t)HDIM * DDIM, HDIM);
        // GEMM1 (both experts): Hs[:, eh*H ..] = w * relu(x @ W1[e] + b1[e])
        gemm1<<<1024, 512, 0, stream>>>(
            xb, W1P, Hs, b1 + (size_t)2 * p * HDIM, wts,
            DDIM, DDIM, KPAIR, DDIM / 64, 32, 16, 2, 2 * p);
        // GEMM2 pair: out += Hs @ W2P^T   (M=8192, N=1024, K=8192)
        gemm2pair<<<256, 512, 0, stream>>>(
            Hs, W2P, out, KPAIR, KPAIR, DDIM, KPAIR / 64, 32, 8, 1);
    }
}

// Round 14
// 1276.812 us; speedup vs baseline: 1.1765x; 1.1765x over previous
//
#include <hip/hip_runtime.h>
#include <hip/hip_bf16.h>

#define DDIM 1024
#define HDIM 4096
#define NEXP 8
#define NROW 8192
#define KPAIR 8192   // 2 experts * HDIM

typedef __attribute__((ext_vector_type(8))) short s16x8;
typedef __attribute__((ext_vector_type(4))) float f32x4;

using bf16 = __hip_bfloat16;

// ---------------------------------------------------------------- helpers
__device__ __forceinline__ void gload16(const bf16* g, bf16* lds) {
    __builtin_amdgcn_global_load_lds(
        (const __attribute__((address_space(1))) unsigned int*)g,
        (__attribute__((address_space(3))) unsigned int*)lds,
        16, 0, 0);
}

template <int N>
__device__ __forceinline__ void wait_vmcnt() {
    if constexpr (N == 6)      asm volatile("s_waitcnt vmcnt(6)" ::: "memory");
    else if constexpr (N == 3) asm volatile("s_waitcnt vmcnt(3)" ::: "memory");
    else                       asm volatile("s_waitcnt vmcnt(0)" ::: "memory");
}

// ---------------------------------------- fused x->bf16 convert + gate softmax
__global__ void cvtgate_kernel(const float* __restrict__ x, const float* __restrict__ Wg,
                               const float* __restrict__ bg, bf16* __restrict__ xb,
                               float* __restrict__ wts) {
    int wave = threadIdx.x >> 6, lane = threadIdx.x & 63;
    int n = blockIdx.x * 4 + wave;
    const float* xr = x + (size_t)n * DDIM;
    bf16* xbr = xb + (size_t)n * DDIM;
    float acc[NEXP] = {0.f, 0.f, 0.f, 0.f, 0.f, 0.f, 0.f, 0.f};
#pragma unroll
    for (int j = 0; j < 4; ++j) {
        int d0 = j * 256 + lane * 4;
        float4 v = *(const float4*)&xr[d0];
        union { bf16 b[4]; uint2 u; } pk;
        pk.b[0] = __float2bfloat16(v.x);
        pk.b[1] = __float2bfloat16(v.y);
        pk.b[2] = __float2bfloat16(v.z);
        pk.b[3] = __float2bfloat16(v.w);
        *(uint2*)&xbr[d0] = pk.u;
        const float* w0 = Wg + (size_t)d0 * NEXP;
#pragma unroll
        for (int e = 0; e < NEXP; ++e)
            acc[e] += v.x * w0[e] + v.y * w0[NEXP + e] + v.z * w0[2 * NEXP + e] +
                      v.w * w0[3 * NEXP + e];
    }
#pragma unroll
    for (int off = 32; off > 0; off >>= 1) {
#pragma unroll
        for (int e = 0; e < NEXP; ++e) acc[e] += __shfl_xor(acc[e], off, 64);
    }
    if (lane == 0) {
        float mx = -1e30f;
#pragma unroll
        for (int e = 0; e < NEXP; ++e) { acc[e] += bg[e]; mx = fmaxf(mx, acc[e]); }
        float s = 0.f;
#pragma unroll
        for (int e = 0; e < NEXP; ++e) { acc[e] = __expf(acc[e] - mx); s += acc[e]; }
        float inv = 1.0f / s;
#pragma unroll
        for (int e = 0; e < NEXP; ++e) wts[(size_t)n * NEXP + e] = acc[e] * inv;
    }
}

// ------------------ fp32 src [R][C] (+z*szs) -> bf16 dst [C][ldo] (+z*dzo)
__global__ void transpose_cvt_kernel(const float* __restrict__ src, bf16* __restrict__ dst,
                                     int R, int C, int ldo, size_t szs, int dzo) {
    __shared__ float t[128][65];
    const float* s = src + (size_t)blockIdx.z * szs;
    bf16* d = dst + (size_t)blockIdx.z * dzo;
    const int r0 = blockIdx.y * 64, c0 = blockIdx.x * 128;
    const int tid = threadIdx.x;
    const int lrow = tid >> 5, lc4 = tid & 31;
#pragma unroll
    for (int i = 0; i < 8; ++i) {
        int rr = i * 8 + lrow;
        float4 v = *(const float4*)&s[(size_t)(r0 + rr) * C + c0 + lc4 * 4];
        t[lc4 * 4 + 0][rr] = v.x;
        t[lc4 * 4 + 1][rr] = v.y;
        t[lc4 * 4 + 2][rr] = v.z;
        t[lc4 * 4 + 3][rr] = v.w;
    }
    __syncthreads();
    const int oc = tid >> 3, oj = tid & 7;
#pragma unroll
    for (int i = 0; i < 4; ++i) {
        int c = oc + i * 32;
        union { bf16 b[8]; s16x8 v; } p;
#pragma unroll
        for (int q = 0; q < 8; ++q) p.b[q] = __float2bfloat16(t[c][oj * 8 + q]);
        *(s16x8*)&d[(size_t)(c0 + c) * ldo + r0 + oj * 8] = p.v;
    }
}

// ------------------------------------------- out[n,d] = sum_e w[n,e]*b2[e,d]
__global__ void out_init_kernel(const float* __restrict__ wts, const float* __restrict__ b2,
                                float* __restrict__ out) {
    size_t idx = (size_t)blockIdx.x * 256 + threadIdx.x;
    int d = (int)(idx & (DDIM - 1));
    size_t n = idx >> 10;
    const float* w = wts + n * NEXP;
    float s = 0.f;
#pragma unroll
    for (int e = 0; e < NEXP; ++e) s += w[e] * b2[(size_t)e * DDIM + d];
    out[idx] = s;
}

// ---------------------------------------------------------------- GEMM1 (8-phase, BK=64)
// BM=256 x BN=256, 8 waves 2(M)x4(N), wave-tile 128x64. PAIR-FUSED dispatch
// (round-11 structure = best replay-measured). Epilogue: Hs =
// wts[row,e]*relu(acc+b1), LDS-buffered coalesced store with granule-XOR
// swizzle (cl ^ ((rl&7)<<3)): 4-way bank alias -> 2-way (free).
__global__ __launch_bounds__(512, 1) void gemm1(
    const bf16* __restrict__ A, const bf16* __restrict__ BTp, bf16* __restrict__ Hsb,
    const float* __restrict__ b1p, const float* __restrict__ wts,
    int lda, int ldb, int ldc, int NT, int tilesM, int tilesN, int XGN, int e0) {
    constexpr int WROWS = 128;
    constexpr int HALFA = 256 * 32;
    constexpr int HALFB = 256 * 32;
    constexpr int ATOT = 2 * HALFA;
    constexpr int BUFE = ATOT + 2 * HALFB;  // 32768 elems
    __shared__ __align__(16) bf16 smem[2 * BUFE];

    const int tid = threadIdx.x;
    const int wave = tid >> 6, lane = tid & 63;
    const int wm = wave >> 2, wn = wave & 3;
    const int r = lane & 15, kg = lane >> 4;

    // expert half of the pair
    const int eh = blockIdx.x >> 9;
    const int bx = blockIdx.x & 511;
    const bf16* BT = BTp + (size_t)eh * HDIM * DDIM;
    bf16* Cout = Hsb + (size_t)eh * HDIM;
    const float* bias = b1p + (size_t)eh * HDIM;
    const int expert = e0 + eh;

    // ---- 2-D XCD-aware tile mapping (round-3 FETCH-verified)
    const int xcd = bx & 7, slot = bx >> 3;
    const int XGM = 8 / XGN;
    const int rm = tilesM / XGM, rn = tilesN / XGN;
    const int g = slot >> 5, u = slot & 31;
    const int gpr = rn >> 3;
    const int gm = (g / gpr) * 4 + (u >> 3);
    const int gn = (g % gpr) * 8 + (u & 7);
    const int tm = (xcd / XGN) * rm + gm;
    const int tn = (xcd % XGN) * rn + gn;

    const bf16* gA = A + (size_t)tm * 256 * lda;
    const bf16* gB = BT + (size_t)tn * 256 * ldb;

    f32x4 acc[8][4];
#pragma unroll
    for (int m = 0; m < 8; ++m)
#pragma unroll
        for (int n = 0; n < 4; ++n) acc[m][n] = (f32x4){0.f, 0.f, 0.f, 0.f};

    auto stageA = [&](int t, int ks) {
        bf16* dst = smem + (t & 1) * BUFE + ks * HALFA;
#pragma unroll
        for (int j = 0; j < 2; ++j) {
            int c = j * 512 + tid;
            int R = c >> 2, kc = (c & 3) ^ ((R >> 1) & 3);
            gload16(gA + (size_t)R * lda + t * 64 + ks * 32 + kc * 8,
                    dst + (j * 512 + wave * 64) * 8);
        }
    };
    auto stageB = [&](int t, int ks) {
        bf16* dst = smem + (t & 1) * BUFE + ATOT + ks * HALFB;
#pragma unroll
        for (int j = 0; j < 2; ++j) {
            int c = j * 512 + tid;
            int R = c >> 2, kc = (c & 3) ^ ((R >> 1) & 3);
            gload16(gB + (size_t)R * ldb + t * 64 + ks * 32 + kc * 8,
                    dst + (j * 512 + wave * 64) * 8);
        }
    };

    s16x8 a0[4], bb[4];
    auto ldA = [&](int buf, int ks, int mh) {
#pragma unroll
        for (int m = 0; m < 4; ++m) {
            int R = wm * WROWS + mh * 64 + m * 16 + r;
            a0[m] = *(const s16x8*)&smem[buf * BUFE + ks * HALFA + R * 32 +
                                         ((kg ^ ((R >> 1) & 3)) * 8)];
        }
    };
    auto ldB = [&](int buf, int ks) {
#pragma unroll
        for (int n = 0; n < 4; ++n) {
            int R = wn * 64 + n * 16 + r;
            bb[n] = *(const s16x8*)&smem[buf * BUFE + ATOT + ks * HALFB + R * 32 +
                                         ((kg ^ ((R >> 1) & 3)) * 8)];
        }
    };

    auto preMFMA = [&]() {
        __builtin_amdgcn_s_barrier();
        asm volatile("s_waitcnt lgkmcnt(0)" ::: "memory");
        __builtin_amdgcn_sched_barrier(0);
        __builtin_amdgcn_s_setprio(1);
    };
    auto postMFMA = [&](bool vm) {
        __builtin_amdgcn_s_setprio(0);
        if (vm) wait_vmcnt<6>();
        __builtin_amdgcn_s_barrier();
    };
    auto mfmaLo = [&]() {
#pragma unroll
        for (int m = 0; m < 4; ++m)
#pragma unroll
            for (int n = 0; n < 4; ++n)
                acc[m][n] = __builtin_amdgcn_mfma_f32_16x16x32_bf16(a0[m], bb[n], acc[m][n], 0, 0, 0);
    };
    auto mfmaHi = [&]() {
#pragma unroll
        for (int m = 0; m < 4; ++m)
#pragma unroll
            for (int n = 0; n < 4; ++n)
                acc[4 + m][n] = __builtin_amdgcn_mfma_f32_16x16x32_bf16(a0[m], bb[n], acc[4 + m][n], 0, 0, 0);
    };

    // prologue
    stageB(0, 0); stageA(0, 0); stageB(0, 1); stageA(0, 1);
    stageB(1, 0); stageA(1, 0); stageB(1, 1);   // A(1,1) staged at iter0 ph1
    wait_vmcnt<6>();
    __builtin_amdgcn_s_barrier();

    const int NI = NT / 2;
    for (int i = 0; i < NI; ++i) {
        const int t0 = 2 * i, t1 = t0 + 1;
        const bool g2 = (t0 + 2 < NT), g3 = (t1 + 2 < NT);
        ldB(0, 0); ldA(0, 0, 0); stageA(t1, 1);
        preMFMA(); mfmaLo(); postMFMA(false);
        ldA(0, 0, 1); if (g2) stageB(t0 + 2, 0);
        preMFMA(); mfmaHi(); postMFMA(false);
        ldB(0, 1); ldA(0, 1, 0); if (g2) stageA(t0 + 2, 0);
        preMFMA(); mfmaLo(); postMFMA(false);
        ldA(0, 1, 1); if (g2) stageB(t0 + 2, 1);
        preMFMA(); mfmaHi(); postMFMA(true);
        ldB(1, 0); ldA(1, 0, 0); if (g2) stageA(t0 + 2, 1);
        preMFMA(); mfmaLo(); postMFMA(false);
        ldA(1, 0, 1); if (g3) stageB(t1 + 2, 0);
        preMFMA(); mfmaHi(); postMFMA(false);
        ldB(1, 1); ldA(1, 1, 0); if (g3) stageA(t1 + 2, 0);
        preMFMA(); mfmaLo(); postMFMA(false);
        ldA(1, 1, 1); if (g3) stageB(t1 + 2, 1);
        preMFMA(); mfmaHi(); postMFMA(true);
    }

    // ---- epilogue: Hs = w * relu(acc + bias), LDS-buffered coalesced store.
    // Granule-XOR swizzle (bijective per row): 4-way alias -> 2-way (free).
    bf16* hs = smem;                         // 65536 elems == 256*256
    const int col0 = tn * 256 + wn * 64;
#pragma unroll
    for (int n = 0; n < 4; ++n) {
        float bv = bias[col0 + n * 16 + r];
        int cl = wn * 64 + n * 16 + r;
#pragma unroll
        for (int mf = 0; mf < 8; ++mf) {
#pragma unroll
            for (int j = 0; j < 4; ++j) {
                int rl = wm * WROWS + (mf >> 2) * 64 + (mf & 3) * 16 + kg * 4 + j;
                float wv = wts[((size_t)tm * 256 + rl) * NEXP + expert];
                float v = acc[mf][n][j] + bv;
                v = v > 0.f ? v : 0.f;
                hs[rl * 256 + (cl ^ ((rl & 7) << 3))] = __float2bfloat16(wv * v);
            }
        }
    }
    __builtin_amdgcn_s_barrier();
    asm volatile("s_waitcnt lgkmcnt(0)" ::: "memory");
    const size_t rbase = (size_t)tm * 256;
    const int cbase = tn * 256;
#pragma unroll
    for (int i2 = 0; i2 < 16; ++i2) {
        int rl = wave * 32 + i2 * 2 + (lane >> 5);
        int c8 = (lane & 31) * 8;
        s16x8 v = *(const s16x8*)&hs[rl * 256 + (c8 ^ ((rl & 7) << 3))];
        *(s16x8*)&Cout[(rbase + rl) * (size_t)ldc + cbase + c8] = v;
    }
}

// ---------------------------------------------------------------- GEMM2 (expert-pair, K=8192)
// Round-10 loop (best measured). ROUND-14: split epilogue with STATIC acc
// indexing — R13's runtime-indexed acc[mfbase+mq] spilled the accumulator to
// scratch (WRITE 32->160 MB, rule #20). Both branches fully unrolled with
// compile-time acc indices; branch is wave-uniform (ksw).
__global__ __launch_bounds__(512, 1) void gemm2pair(
    const bf16* __restrict__ A, const bf16* __restrict__ BT, float* __restrict__ O,
    int lda, int ldb, int ldc, int NT, int tilesM, int tilesN, int XGN) {
    constexpr int HALFA = 256 * 32;          // 8192 elems
    constexpr int HALFB = 128 * 32;          // 4096 elems
    constexpr int ATOT = 2 * HALFA;
    constexpr int BUFE = ATOT + 2 * HALFB;   // 24576 elems
    constexpr int RSTR = 68;                 // padded reduce stride (f32)
    __shared__ __align__(16) bf16 smem[3 * BUFE];   // 144 KiB

    const int tid = threadIdx.x;
    const int wave = tid >> 6, lane = tid & 63;
    const int ksw = wave & 1, wn = (wave >> 1) & 1, wm = wave >> 2;
    const int r = lane & 15, kg = lane >> 4;

    // ---- 2-D XCD-aware tile mapping (round-3 FETCH-verified)
    const int xcd = blockIdx.x & 7, slot = blockIdx.x >> 3;
    const int XGM = 8 / XGN;
    const int rm = tilesM / XGM, rn = tilesN / XGN;
    const int g = slot >> 5, u = slot & 31;
    const int gpr = rn >> 3;
    const int gm = (g / gpr) * 4 + (u >> 3);
    const int gn = (g % gpr) * 8 + (u & 7);
    const int tm = (xcd / XGN) * rm + gm;
    const int tn = (xcd % XGN) * rn + gn;

    const bf16* gA = A + (size_t)tm * 256 * lda;
    const bf16* gB = BT + (size_t)tn * 128 * ldb;

    f32x4 acc[8][4];
#pragma unroll
    for (int m = 0; m < 8; ++m)
#pragma unroll
        for (int n = 0; n < 4; ++n) acc[m][n] = (f32x4){0.f, 0.f, 0.f, 0.f};

    auto stageA = [&](int t, int ks) {
        bf16* dst = smem + (t % 3) * BUFE + ks * HALFA;
#pragma unroll
        for (int j = 0; j < 2; ++j) {
            int c = j * 512 + tid;
            int R = c >> 2, kc = (c & 3) ^ ((R >> 1) & 3);
            gload16(gA + (size_t)R * lda + t * 64 + ks * 32 + kc * 8,
                    dst + (j * 512 + wave * 64) * 8);
        }
    };
    auto stageB = [&](int t, int ks) {
        bf16* dst = smem + (t % 3) * BUFE + ATOT + ks * HALFB;
        int R = tid >> 2, kc = (tid & 3) ^ ((R >> 1) & 3);
        gload16(gB + (size_t)R * ldb + t * 64 + ks * 32 + kc * 8, dst + (wave * 64) * 8);
    };

    s16x8 a0[4], a1[4], bfr[4];
    auto ldA0 = [&](int rb) {
#pragma unroll
        for (int m = 0; m < 4; ++m) {
            int R = wm * 128 + m * 16 + r;
            a0[m] = *(const s16x8*)&smem[rb * BUFE + ksw * HALFA + R * 32 +
                                         ((kg ^ ((R >> 1) & 3)) * 8)];
        }
    };
    auto ldA1 = [&](int rb) {
#pragma unroll
        for (int m = 0; m < 4; ++m) {
            int R = wm * 128 + 64 + m * 16 + r;
            a1[m] = *(const s16x8*)&smem[rb * BUFE + ksw * HALFA + R * 32 +
                                         ((kg ^ ((R >> 1) & 3)) * 8)];
        }
    };
    auto ldB = [&](int rb) {
#pragma unroll
        for (int n = 0; n < 4; ++n) {
            int R = wn * 64 + n * 16 + r;
            bfr[n] = *(const s16x8*)&smem[rb * BUFE + ATOT + ksw * HALFB + R * 32 +
                                          ((kg ^ ((R >> 1) & 3)) * 8)];
        }
    };

    // prologue: stage tiles 0,1 (6 insts each)
    stageA(0, 0); stageB(0, 0); stageA(0, 1); stageB(0, 1);
    stageA(1, 0); stageB(1, 0); stageA(1, 1); stageB(1, 1);
    wait_vmcnt<6>();                        // tile 0 resident; tile 1 in flight
    __builtin_amdgcn_s_barrier();

    for (int t = 0; t < NT; ++t) {
        const int rb = t % 3;
        const bool gg = (t + 2 < NT);
        ldB(rb); ldA0(rb);
        if (gg) { stageA(t + 2, 0); stageB(t + 2, 0); }
        ldA1(rb);
        if (gg) { stageA(t + 2, 1); stageB(t + 2, 1); }
        asm volatile("s_waitcnt lgkmcnt(4)" ::: "memory");
        __builtin_amdgcn_sched_barrier(0);
        __builtin_amdgcn_s_setprio(1);
#pragma unroll
        for (int m = 0; m < 4; ++m)
#pragma unroll
            for (int n = 0; n < 4; ++n)
                acc[m][n] = __builtin_amdgcn_mfma_f32_16x16x32_bf16(a0[m], bfr[n], acc[m][n], 0, 0, 0);
        __builtin_amdgcn_s_setprio(0);
        asm volatile("s_waitcnt lgkmcnt(0)" ::: "memory");
        __builtin_amdgcn_sched_barrier(0);
        __builtin_amdgcn_s_setprio(1);
#pragma unroll
        for (int m = 0; m < 4; ++m)
#pragma unroll
            for (int n = 0; n < 4; ++n)
                acc[4 + m][n] = __builtin_amdgcn_mfma_f32_16x16x32_bf16(a1[m], bfr[n], acc[4 + m][n], 0, 0, 0);
        __builtin_amdgcn_s_setprio(0);
        if (t + 1 < NT) {
            if (gg) wait_vmcnt<6>();
            else    wait_vmcnt<0>();
            __builtin_amdgcn_s_barrier();
        }
    }

    // ---- split cross-ksw reduce (STATIC acc indices in each branch):
    // ksw1 dumps lo-half (acc[0..3]) rows 0-63; ksw0 dumps hi-half
    // (acc[4..7]) rows 64-127; each wave RMWs the half it kept.
    __syncthreads();                         // ring buffers dead
    float* red = (float*)smem;
    const int zb0 = ((wm * 2 + wn) * 2 + 0) * (64 * RSTR);   // rows 0-63
    const int zb1 = ((wm * 2 + wn) * 2 + 1) * (64 * RSTR);   // rows 64-127
    if (ksw == 1) {
#pragma unroll
        for (int mq = 0; mq < 4; ++mq) {
#pragma unroll
            for (int n = 0; n < 4; ++n) {
                int rl = mq * 16 + kg * 4;
                int cl = n * 16 + r;
#pragma unroll
                for (int j = 0; j < 4; ++j)
                    red[zb0 + (rl + j) * RSTR + cl] = acc[mq][n][j];
            }
        }
    } else {
#pragma unroll
        for (int mq = 0; mq < 4; ++mq) {
#pragma unroll
            for (int n = 0; n < 4; ++n) {
                int rl = mq * 16 + kg * 4;
                int cl = n * 16 + r;
#pragma unroll
                for (int j = 0; j < 4; ++j)
                    red[zb1 + (rl + j) * RSTR + cl] = acc[4 + mq][n][j];
            }
        }
    }
    __syncthreads();
    const int col0 = tn * 128 + wn * 64;
    if (ksw == 0) {
        const size_t row0 = (size_t)tm * 256 + wm * 128;
#pragma unroll
        for (int mq = 0; mq < 4; ++mq) {
#pragma unroll
            for (int j = 0; j < 4; ++j) {
                int rl = mq * 16 + kg * 4 + j;
                size_t rr = row0 + rl;
#pragma unroll
                for (int n = 0; n < 4; ++n) {
                    int cl = n * 16 + r;
                    float v = acc[mq][n][j] + red[zb0 + rl * RSTR + cl];
                    O[rr * (size_t)ldc + col0 + cl] += v;
                }
            }
        }
    } else {
        const size_t row0 = (size_t)tm * 256 + wm * 128 + 64;
#pragma unroll
        for (int mq = 0; mq < 4; ++mq) {
#pragma unroll
            for (int j = 0; j < 4; ++j) {
                int rl = mq * 16 + kg * 4 + j;
                size_t rr = row0 + rl;
#pragma unroll
                for (int n = 0; n < 4; ++n) {
                    int cl = n * 16 + r;
                    float v = acc[4 + mq][n][j] + red[zb1 + rl * RSTR + cl];
                    O[rr * (size_t)ldc + col0 + cl] += v;
                }
            }
        }
    }
}

// ---------------------------------------------------------------- launch
extern "C" void kernel_launch(void* const* d_in, const int* in_sizes, int n_in,
                              void* d_out, int out_size, void* d_ws, size_t ws_size,
                              hipStream_t stream) {
    const float* x  = (const float*)d_in[0];
    const float* Wg = (const float*)d_in[1];
    const float* bg = (const float*)d_in[2];
    const float* W1 = (const float*)d_in[3];
    const float* b1 = (const float*)d_in[4];
    const float* W2 = (const float*)d_in[5];
    const float* b2 = (const float*)d_in[6];
    float* out = (float*)d_out;

    char* ws = (char*)d_ws;
    bf16* xb   = (bf16*)(ws);                          // 16 MiB  [N][D]
    bf16* W1P  = (bf16*)(ws + (16ull << 20));          // 16 MiB  [2][H][D] (pair)
    bf16* W2P  = (bf16*)(ws + (32ull << 20));          // 16 MiB  [D][KPAIR] (pair)
    bf16* Hs   = (bf16*)(ws + (48ull << 20));          // 128 MiB [N][KPAIR] (pair)
    float* wts = (float*)(ws + (176ull << 20));        // 256 KiB [N][E]

    cvtgate_kernel<<<NROW / 4, 256, 0, stream>>>(x, Wg, bg, xb, wts);
    out_init_kernel<<<NROW * DDIM / 256, 256, 0, stream>>>(wts, b2, out);

    for (int p = 0; p < 4; ++p) {
        // W1 pair: [2][D][H] -> W1P [2][H][D]
        transpose_cvt_kernel<<<dim3(HDIM / 128, DDIM / 64, 2), 256, 0, stream>>>(
            W1 + (size_t)2 * p * DDIM * HDIM, W1P, DDIM, HDIM, DDIM,
            (size_t)DDIM * HDIM, HDIM * DDIM);
        // GEMM1 (both experts): Hs[:, eh*H ..] = w * relu(x @ W1[e] + b1[e])
        gemm1<<<1024, 512, 0, stream>>>(
            xb, W1P, Hs, b1 + (size_t)2 * p * HDIM, wts,
            DDIM, DDIM, KPAIR, DDIM / 64, 32, 16, 2, 2 * p);
        // W2 pair: [2][H][D] -> W2P [D][KPAIR] (after G1: stays L2-hot for G2)
        transpose_cvt_kernel<<<dim3(DDIM / 128, HDIM / 64, 2), 256, 0, stream>>>(
            W2 + (size_t)2 * p * HDIM * DDIM, W2P, HDIM, DDIM, KPAIR,
            (size_t)HDIM * DDIM, HDIM);
        // GEMM2 pair: out += Hs @ W2P^T   (M=8192, N=1024, K=8192)
        gemm2pair<<<256, 512, 0, stream>>>(
            Hs, W2P, out, KPAIR, KPAIR, DDIM, KPAIR / 64, 32, 8, 1);
    }
}

// Round 15
// 1262.131 us; speedup vs baseline: 1.1902x; 1.0116x over previous
//
#include <hip/hip_runtime.h>
#include <hip/hip_bf16.h>

#define DDIM 1024
#define HDIM 4096
#define NEXP 8
#define NROW 8192
#define KPAIR 8192   // 2 experts * HDIM

typedef __attribute__((ext_vector_type(8))) short s16x8;
typedef __attribute__((ext_vector_type(4))) float f32x4;

using bf16 = __hip_bfloat16;

// ---------------------------------------------------------------- helpers
__device__ __forceinline__ void gload16(const bf16* g, bf16* lds) {
    __builtin_amdgcn_global_load_lds(
        (const __attribute__((address_space(1))) unsigned int*)g,
        (__attribute__((address_space(3))) unsigned int*)lds,
        16, 0, 0);
}

template <int N>
__device__ __forceinline__ void wait_vmcnt() {
    if constexpr (N == 6)      asm volatile("s_waitcnt vmcnt(6)" ::: "memory");
    else if constexpr (N == 3) asm volatile("s_waitcnt vmcnt(3)" ::: "memory");
    else                       asm volatile("s_waitcnt vmcnt(0)" ::: "memory");
}

// ---------------------------------------- fused x->bf16 convert + gate softmax
__global__ void cvtgate_kernel(const float* __restrict__ x, const float* __restrict__ Wg,
                               const float* __restrict__ bg, bf16* __restrict__ xb,
                               float* __restrict__ wts) {
    int wave = threadIdx.x >> 6, lane = threadIdx.x & 63;
    int n = blockIdx.x * 4 + wave;
    const float* xr = x + (size_t)n * DDIM;
    bf16* xbr = xb + (size_t)n * DDIM;
    float acc[NEXP] = {0.f, 0.f, 0.f, 0.f, 0.f, 0.f, 0.f, 0.f};
#pragma unroll
    for (int j = 0; j < 4; ++j) {
        int d0 = j * 256 + lane * 4;
        float4 v = *(const float4*)&xr[d0];
        union { bf16 b[4]; uint2 u; } pk;
        pk.b[0] = __float2bfloat16(v.x);
        pk.b[1] = __float2bfloat16(v.y);
        pk.b[2] = __float2bfloat16(v.z);
        pk.b[3] = __float2bfloat16(v.w);
        *(uint2*)&xbr[d0] = pk.u;
        const float* w0 = Wg + (size_t)d0 * NEXP;
#pragma unroll
        for (int e = 0; e < NEXP; ++e)
            acc[e] += v.x * w0[e] + v.y * w0[NEXP + e] + v.z * w0[2 * NEXP + e] +
                      v.w * w0[3 * NEXP + e];
    }
#pragma unroll
    for (int off = 32; off > 0; off >>= 1) {
#pragma unroll
        for (int e = 0; e < NEXP; ++e) acc[e] += __shfl_xor(acc[e], off, 64);
    }
    if (lane == 0) {
        float mx = -1e30f;
#pragma unroll
        for (int e = 0; e < NEXP; ++e) { acc[e] += bg[e]; mx = fmaxf(mx, acc[e]); }
        float s = 0.f;
#pragma unroll
        for (int e = 0; e < NEXP; ++e) { acc[e] = __expf(acc[e] - mx); s += acc[e]; }
        float inv = 1.0f / s;
#pragma unroll
        for (int e = 0; e < NEXP; ++e) wts[(size_t)n * NEXP + e] = acc[e] * inv;
    }
}

// ------------------ fp32 src [R][C] (+z*szs) -> bf16 dst [C][ldo] (+z*dzo)
__global__ void transpose_cvt_kernel(const float* __restrict__ src, bf16* __restrict__ dst,
                                     int R, int C, int ldo, size_t szs, int dzo) {
    __shared__ float t[128][65];
    const float* s = src + (size_t)blockIdx.z * szs;
    bf16* d = dst + (size_t)blockIdx.z * dzo;
    const int r0 = blockIdx.y * 64, c0 = blockIdx.x * 128;
    const int tid = threadIdx.x;
    const int lrow = tid >> 5, lc4 = tid & 31;
#pragma unroll
    for (int i = 0; i < 8; ++i) {
        int rr = i * 8 + lrow;
        float4 v = *(const float4*)&s[(size_t)(r0 + rr) * C + c0 + lc4 * 4];
        t[lc4 * 4 + 0][rr] = v.x;
        t[lc4 * 4 + 1][rr] = v.y;
        t[lc4 * 4 + 2][rr] = v.z;
        t[lc4 * 4 + 3][rr] = v.w;
    }
    __syncthreads();
    const int oc = tid >> 3, oj = tid & 7;
#pragma unroll
    for (int i = 0; i < 4; ++i) {
        int c = oc + i * 32;
        union { bf16 b[8]; s16x8 v; } p;
#pragma unroll
        for (int q = 0; q < 8; ++q) p.b[q] = __float2bfloat16(t[c][oj * 8 + q]);
        *(s16x8*)&d[(size_t)(c0 + c) * ldo + r0 + oj * 8] = p.v;
    }
}

// ------------------------------------------- out[n,d] = sum_e w[n,e]*b2[e,d]
__global__ void out_init_kernel(const float* __restrict__ wts, const float* __restrict__ b2,
                                float* __restrict__ out) {
    size_t idx = (size_t)blockIdx.x * 256 + threadIdx.x;
    int d = (int)(idx & (DDIM - 1));
    size_t n = idx >> 10;
    const float* w = wts + n * NEXP;
    float s = 0.f;
#pragma unroll
    for (int e = 0; e < NEXP; ++e) s += w[e] * b2[(size_t)e * DDIM + d];
    out[idx] = s;
}

// ---------------------------------------------------------------- GEMM1 (8-phase, BK=64)
// BM=256 x BN=256, 8 waves 2(M)x4(N), wave-tile 128x64. PAIR-FUSED dispatch
// (round-11/14 structure = best measured). Epilogue: Hs =
// wts[row,e]*relu(acc+b1), LDS-buffered coalesced store with granule-XOR
// swizzle (verified: conflicts 2.1M -> 0, round 14).
__global__ __launch_bounds__(512, 1) void gemm1(
    const bf16* __restrict__ A, const bf16* __restrict__ BTp, bf16* __restrict__ Hsb,
    const float* __restrict__ b1p, const float* __restrict__ wts,
    int lda, int ldb, int ldc, int NT, int tilesM, int tilesN, int XGN, int e0) {
    constexpr int WROWS = 128;
    constexpr int HALFA = 256 * 32;
    constexpr int HALFB = 256 * 32;
    constexpr int ATOT = 2 * HALFA;
    constexpr int BUFE = ATOT + 2 * HALFB;  // 32768 elems
    __shared__ __align__(16) bf16 smem[2 * BUFE];

    const int tid = threadIdx.x;
    const int wave = tid >> 6, lane = tid & 63;
    const int wm = wave >> 2, wn = wave & 3;
    const int r = lane & 15, kg = lane >> 4;

    const int eh = blockIdx.x >> 9;
    const int bx = blockIdx.x & 511;
    const bf16* BT = BTp + (size_t)eh * HDIM * DDIM;
    bf16* Cout = Hsb + (size_t)eh * HDIM;
    const float* bias = b1p + (size_t)eh * HDIM;
    const int expert = e0 + eh;

    // ---- 2-D XCD-aware tile mapping (round-3 FETCH-verified)
    const int xcd = bx & 7, slot = bx >> 3;
    const int XGM = 8 / XGN;
    const int rm = tilesM / XGM, rn = tilesN / XGN;
    const int g = slot >> 5, u = slot & 31;
    const int gpr = rn >> 3;
    const int gm = (g / gpr) * 4 + (u >> 3);
    const int gn = (g % gpr) * 8 + (u & 7);
    const int tm = (xcd / XGN) * rm + gm;
    const int tn = (xcd % XGN) * rn + gn;

    const bf16* gA = A + (size_t)tm * 256 * lda;
    const bf16* gB = BT + (size_t)tn * 256 * ldb;

    f32x4 acc[8][4];
#pragma unroll
    for (int m = 0; m < 8; ++m)
#pragma unroll
        for (int n = 0; n < 4; ++n) acc[m][n] = (f32x4){0.f, 0.f, 0.f, 0.f};

    auto stageA = [&](int t, int ks) {
        bf16* dst = smem + (t & 1) * BUFE + ks * HALFA;
#pragma unroll
        for (int j = 0; j < 2; ++j) {
            int c = j * 512 + tid;
            int R = c >> 2, kc = (c & 3) ^ ((R >> 1) & 3);
            gload16(gA + (size_t)R * lda + t * 64 + ks * 32 + kc * 8,
                    dst + (j * 512 + wave * 64) * 8);
        }
    };
    auto stageB = [&](int t, int ks) {
        bf16* dst = smem + (t & 1) * BUFE + ATOT + ks * HALFB;
#pragma unroll
        for (int j = 0; j < 2; ++j) {
            int c = j * 512 + tid;
            int R = c >> 2, kc = (c & 3) ^ ((R >> 1) & 3);
            gload16(gB + (size_t)R * ldb + t * 64 + ks * 32 + kc * 8,
                    dst + (j * 512 + wave * 64) * 8);
        }
    };

    s16x8 a0[4], bb[4];
    auto ldA = [&](int buf, int ks, int mh) {
#pragma unroll
        for (int m = 0; m < 4; ++m) {
            int R = wm * WROWS + mh * 64 + m * 16 + r;
            a0[m] = *(const s16x8*)&smem[buf * BUFE + ks * HALFA + R * 32 +
                                         ((kg ^ ((R >> 1) & 3)) * 8)];
        }
    };
    auto ldB = [&](int buf, int ks) {
#pragma unroll
        for (int n = 0; n < 4; ++n) {
            int R = wn * 64 + n * 16 + r;
            bb[n] = *(const s16x8*)&smem[buf * BUFE + ATOT + ks * HALFB + R * 32 +
                                         ((kg ^ ((R >> 1) & 3)) * 8)];
        }
    };

    auto preMFMA = [&]() {
        __builtin_amdgcn_s_barrier();
        asm volatile("s_waitcnt lgkmcnt(0)" ::: "memory");
        __builtin_amdgcn_sched_barrier(0);
        __builtin_amdgcn_s_setprio(1);
    };
    auto postMFMA = [&](bool vm) {
        __builtin_amdgcn_s_setprio(0);
        if (vm) wait_vmcnt<6>();
        __builtin_amdgcn_s_barrier();
    };
    auto mfmaLo = [&]() {
#pragma unroll
        for (int m = 0; m < 4; ++m)
#pragma unroll
            for (int n = 0; n < 4; ++n)
                acc[m][n] = __builtin_amdgcn_mfma_f32_16x16x32_bf16(a0[m], bb[n], acc[m][n], 0, 0, 0);
    };
    auto mfmaHi = [&]() {
#pragma unroll
        for (int m = 0; m < 4; ++m)
#pragma unroll
            for (int n = 0; n < 4; ++n)
                acc[4 + m][n] = __builtin_amdgcn_mfma_f32_16x16x32_bf16(a0[m], bb[n], acc[4 + m][n], 0, 0, 0);
    };

    // prologue
    stageB(0, 0); stageA(0, 0); stageB(0, 1); stageA(0, 1);
    stageB(1, 0); stageA(1, 0); stageB(1, 1);   // A(1,1) staged at iter0 ph1
    wait_vmcnt<6>();
    __builtin_amdgcn_s_barrier();

    const int NI = NT / 2;
    for (int i = 0; i < NI; ++i) {
        const int t0 = 2 * i, t1 = t0 + 1;
        const bool g2 = (t0 + 2 < NT), g3 = (t1 + 2 < NT);
        ldB(0, 0); ldA(0, 0, 0); stageA(t1, 1);
        preMFMA(); mfmaLo(); postMFMA(false);
        ldA(0, 0, 1); if (g2) stageB(t0 + 2, 0);
        preMFMA(); mfmaHi(); postMFMA(false);
        ldB(0, 1); ldA(0, 1, 0); if (g2) stageA(t0 + 2, 0);
        preMFMA(); mfmaLo(); postMFMA(false);
        ldA(0, 1, 1); if (g2) stageB(t0 + 2, 1);
        preMFMA(); mfmaHi(); postMFMA(true);
        ldB(1, 0); ldA(1, 0, 0); if (g2) stageA(t0 + 2, 1);
        preMFMA(); mfmaLo(); postMFMA(false);
        ldA(1, 0, 1); if (g3) stageB(t1 + 2, 0);
        preMFMA(); mfmaHi(); postMFMA(false);
        ldB(1, 1); ldA(1, 1, 0); if (g3) stageA(t1 + 2, 0);
        preMFMA(); mfmaLo(); postMFMA(false);
        ldA(1, 1, 1); if (g3) stageB(t1 + 2, 1);
        preMFMA(); mfmaHi(); postMFMA(true);
    }

    // ---- epilogue: Hs = w * relu(acc + bias), LDS-buffered coalesced store.
    bf16* hs = smem;                         // 65536 elems == 256*256
    const int col0 = tn * 256 + wn * 64;
#pragma unroll
    for (int n = 0; n < 4; ++n) {
        float bv = bias[col0 + n * 16 + r];
        int cl = wn * 64 + n * 16 + r;
#pragma unroll
        for (int mf = 0; mf < 8; ++mf) {
#pragma unroll
            for (int j = 0; j < 4; ++j) {
                int rl = wm * WROWS + (mf >> 2) * 64 + (mf & 3) * 16 + kg * 4 + j;
                float wv = wts[((size_t)tm * 256 + rl) * NEXP + expert];
                float v = acc[mf][n][j] + bv;
                v = v > 0.f ? v : 0.f;
                hs[rl * 256 + (cl ^ ((rl & 7) << 3))] = __float2bfloat16(wv * v);
            }
        }
    }
    __builtin_amdgcn_s_barrier();
    asm volatile("s_waitcnt lgkmcnt(0)" ::: "memory");
    const size_t rbase = (size_t)tm * 256;
    const int cbase = tn * 256;
#pragma unroll
    for (int i2 = 0; i2 < 16; ++i2) {
        int rl = wave * 32 + i2 * 2 + (lane >> 5);
        int c8 = (lane & 31) * 8;
        s16x8 v = *(const s16x8*)&hs[rl * 256 + (c8 ^ ((rl & 7) << 3))];
        *(s16x8*)&Cout[(rbase + rl) * (size_t)ldc + cbase + c8] = v;
    }
}

// ---------------------------------------------------------------- GEMM2 v2 (expert-pair, K=8192)
// ROUND-15: 2 blocks/CU for latency hiding. BM=128 x BN=128, BK=64, 4 waves
// (256 thr) = 2(N) x 2(Ksw); wave-tile 128x64 over one 32-k half (12 ds_reads
// / 32 MFMA = 0.375, the proven ratio). dbuf-2 LDS = 64 KiB -> 2 blocks/CU;
// grid 64x8 = 512 = 2/CU. Independent co-resident blocks desynchronize ->
// one block's MFMA hides the other's barrier/drain stalls.
// Stage schedule (stage-one-phase-after-last-read, hand-verified):
//   ph1(t): read B + A-rh1; stage A-rh0(t+1) [other buf];
//   ph2(t): read A-rh0; stage A-rh1(t+2)+B(t+2) [this buf, regions read ph1];
//   vmcnt(6) at ph2 end keeps A-rh0(t+1) resident, 6 newest (t+2) in flight.
// Split reduce in two rounds (static acc indices, rule #20).
__global__ __launch_bounds__(256, 2) void gemm2p(
    const bf16* __restrict__ A, const bf16* __restrict__ BT, float* __restrict__ O,
    int lda, int ldb, int ldc, int NT, int tilesM, int tilesN, int XGN) {
    constexpr int HALFA = 128 * 32;          // 4096 elems (one ks half of A)
    constexpr int HALFB = 128 * 32;          // 4096 elems (one ks half of B)
    constexpr int ATOT = 2 * HALFA;          // 8192
    constexpr int BUFE = ATOT + 2 * HALFB;   // 16384 elems = 32 KiB
    constexpr int RSTR = 68;                 // padded reduce stride (f32)
    __shared__ __align__(16) bf16 smem[2 * BUFE];   // 64 KiB -> 2 blocks/CU

    const int tid = threadIdx.x;
    const int wave = tid >> 6, lane = tid & 63;
    const int ksw = wave & 1, wn = wave >> 1;
    const int r = lane & 15, kg = lane >> 4;

    // ---- 2-D XCD-aware tile mapping (tilesM=64, tilesN=8, XGN=1)
    const int xcd = blockIdx.x & 7, slot = blockIdx.x >> 3;
    const int XGM = 8 / XGN;
    const int rm = tilesM / XGM, rn = tilesN / XGN;
    const int g = slot >> 5, u = slot & 31;
    const int gpr = rn >> 3;
    const int gm = (g / gpr) * 4 + (u >> 3);
    const int gn = (g % gpr) * 8 + (u & 7);
    const int tm = (xcd / XGN) * rm + gm;
    const int tn = (xcd % XGN) * rn + gn;

    const bf16* gA = A + (size_t)tm * 128 * lda;
    const bf16* gB = BT + (size_t)tn * 128 * ldb;

    f32x4 acc[8][4];
#pragma unroll
    for (int m = 0; m < 8; ++m)
#pragma unroll
        for (int n = 0; n < 4; ++n) acc[m][n] = (f32x4){0.f, 0.f, 0.f, 0.f};

    // stage A row-half rh (rows rh*64..rh*64+63) of BOTH ks halves: 2 insts
    auto stageA_rh = [&](int t, int rh) {
        bf16* base = smem + (t & 1) * BUFE;
#pragma unroll
        for (int j = 0; j < 2; ++j) {         // j == ks
            int c = j * 256 + tid;            // chunk within (ks, rh)
            int Rl = (c >> 2) & 63;
            int R = rh * 64 + Rl;
            int kc = (c & 3) ^ ((R >> 1) & 3);
            gload16(gA + (size_t)R * lda + t * 64 + j * 32 + kc * 8,
                    base + j * HALFA + rh * 2048 + ((c & 255) - lane) * 8 + lane * 8);
        }
    };
    // stage full B tile (both ks halves): 4 insts
    auto stageB = [&](int t) {
        bf16* base = smem + (t & 1) * BUFE + ATOT;
#pragma unroll
        for (int j = 0; j < 4; ++j) {
            int c = j * 256 + tid;
            int ks = c >> 9;
            int R = (c >> 2) & 127;
            int kc = (c & 3) ^ ((R >> 1) & 3);
            gload16(gB + (size_t)R * ldb + t * 64 + ks * 32 + kc * 8,
                    base + ks * HALFB + ((c & 511) - lane) * 8 + lane * 8);
        }
    };

    s16x8 afr[4], bfr[4];
    auto ldA = [&](int b, int mh) {           // rows mh*64 .. +63 of own ks
#pragma unroll
        for (int m = 0; m < 4; ++m) {
            int R = mh * 64 + m * 16 + r;
            afr[m] = *(const s16x8*)&smem[b * BUFE + ksw * HALFA + R * 32 +
                                          ((kg ^ ((R >> 1) & 3)) * 8)];
        }
    };
    auto ldB = [&](int b) {
#pragma unroll
        for (int n = 0; n < 4; ++n) {
            int R = wn * 64 + n * 16 + r;
            bfr[n] = *(const s16x8*)&smem[b * BUFE + ATOT + ksw * HALFB + R * 32 +
                                          ((kg ^ ((R >> 1) & 3)) * 8)];
        }
    };

    auto preMFMA = [&]() {
        __builtin_amdgcn_s_barrier();
        asm volatile("s_waitcnt lgkmcnt(0)" ::: "memory");
        __builtin_amdgcn_sched_barrier(0);
        __builtin_amdgcn_s_setprio(1);
    };

    // prologue: t0 full (8 insts), t1 minus A-rh0 (6 insts)
    stageA_rh(0, 0); stageA_rh(0, 1); stageB(0);
    stageA_rh(1, 1); stageB(1);
    wait_vmcnt<6>();                          // t0 resident; t1's 6 in flight
    __builtin_amdgcn_s_barrier();

    for (int t = 0; t < NT; ++t) {
        const int b = t & 1;
        // ---- ph1: read B + A-rh1 (own ks); stage A-rh0(t+1) [other buf]
        ldB(b); ldA(b, 1);
        if (t + 1 < NT) stageA_rh(t + 1, 0);
        preMFMA();
#pragma unroll
        for (int m = 0; m < 4; ++m)
#pragma unroll
            for (int n = 0; n < 4; ++n)
                acc[4 + m][n] = __builtin_amdgcn_mfma_f32_16x16x32_bf16(afr[m], bfr[n], acc[4 + m][n], 0, 0, 0);
        __builtin_amdgcn_s_setprio(0);
        __builtin_amdgcn_s_barrier();
        // ---- ph2: read A-rh0; stage A-rh1(t+2)+B(t+2) [this buf]
        ldA(b, 0);
        if (t + 2 < NT) { stageA_rh(t + 2, 1); stageB(t + 2); }
        preMFMA();
#pragma unroll
        for (int m = 0; m < 4; ++m)
#pragma unroll
            for (int n = 0; n < 4; ++n)
                acc[m][n] = __builtin_amdgcn_mfma_f32_16x16x32_bf16(afr[m], bfr[n], acc[m][n], 0, 0, 0);
        __builtin_amdgcn_s_setprio(0);
        if (t + 1 < NT) {
            if (t + 2 < NT) wait_vmcnt<6>();  // t+1 fully resident
            else            wait_vmcnt<0>();
            __builtin_amdgcn_s_barrier();
        }
    }

    // ---- split cross-ksw reduce, two rounds (zones fit 64 KiB), static idx
    __syncthreads();                          // buffers dead, all loads drained
    float* red = (float*)smem;
    const int zone = wn * (64 * RSTR);
    const int col0 = tn * 128 + wn * 64;
    const size_t row0 = (size_t)tm * 128;
    // Round A: rows 0-63 (acc[0..3])
    if (ksw == 1) {
#pragma unroll
        for (int mq = 0; mq < 4; ++mq)
#pragma unroll
            for (int n = 0; n < 4; ++n) {
                int rl = mq * 16 + kg * 4;
                int cl = n * 16 + r;
#pragma unroll
                for (int j = 0; j < 4; ++j)
                    red[zone + (rl + j) * RSTR + cl] = acc[mq][n][j];
            }
    }
    __syncthreads();
    if (ksw == 0) {
#pragma unroll
        for (int mq = 0; mq < 4; ++mq)
#pragma unroll
            for (int j = 0; j < 4; ++j) {
                int rl = mq * 16 + kg * 4 + j;
                size_t rr = row0 + rl;
#pragma unroll
                for (int n = 0; n < 4; ++n) {
                    int cl = n * 16 + r;
                    O[rr * (size_t)ldc + col0 + cl] += acc[mq][n][j] + red[zone + rl * RSTR + cl];
                }
            }
    }
    __syncthreads();
    // Round B: rows 64-127 (acc[4..7])
    if (ksw == 0) {
#pragma unroll
        for (int mq = 0; mq < 4; ++mq)
#pragma unroll
            for (int n = 0; n < 4; ++n) {
                int rl = mq * 16 + kg * 4;
                int cl = n * 16 + r;
#pragma unroll
                for (int j = 0; j < 4; ++j)
                    red[zone + (rl + j) * RSTR + cl] = acc[4 + mq][n][j];
            }
    }
    __syncthreads();
    if (ksw == 1) {
#pragma unroll
        for (int mq = 0; mq < 4; ++mq)
#pragma unroll
            for (int j = 0; j < 4; ++j) {
                int rl = mq * 16 + kg * 4 + j;
                size_t rr = row0 + 64 + rl;
#pragma unroll
                for (int n = 0; n < 4; ++n) {
                    int cl = n * 16 + r;
                    O[rr * (size_t)ldc + col0 + cl] += acc[4 + mq][n][j] + red[zone + rl * RSTR + cl];
                }
            }
    }
}

// ---------------------------------------------------------------- launch
extern "C" void kernel_launch(void* const* d_in, const int* in_sizes, int n_in,
                              void* d_out, int out_size, void* d_ws, size_t ws_size,
                              hipStream_t stream) {
    const float* x  = (const float*)d_in[0];
    const float* Wg = (const float*)d_in[1];
    const float* bg = (const float*)d_in[2];
    const float* W1 = (const float*)d_in[3];
    const float* b1 = (const float*)d_in[4];
    const float* W2 = (const float*)d_in[5];
    const float* b2 = (const float*)d_in[6];
    float* out = (float*)d_out;

    char* ws = (char*)d_ws;
    bf16* xb   = (bf16*)(ws);                          // 16 MiB  [N][D]
    bf16* W1P  = (bf16*)(ws + (16ull << 20));          // 16 MiB  [2][H][D] (pair)
    bf16* W2P  = (bf16*)(ws + (32ull << 20));          // 16 MiB  [D][KPAIR] (pair)
    bf16* Hs   = (bf16*)(ws + (48ull << 20));          // 128 MiB [N][KPAIR] (pair)
    float* wts = (float*)(ws + (176ull << 20));        // 256 KiB [N][E]

    cvtgate_kernel<<<NROW / 4, 256, 0, stream>>>(x, Wg, bg, xb, wts);
    out_init_kernel<<<NROW * DDIM / 256, 256, 0, stream>>>(wts, b2, out);

    for (int p = 0; p < 4; ++p) {
        // W1 pair: [2][D][H] -> W1P [2][H][D]
        transpose_cvt_kernel<<<dim3(HDIM / 128, DDIM / 64, 2), 256, 0, stream>>>(
            W1 + (size_t)2 * p * DDIM * HDIM, W1P, DDIM, HDIM, DDIM,
            (size_t)DDIM * HDIM, HDIM * DDIM);
        // GEMM1 (both experts): Hs[:, eh*H ..] = w * relu(x @ W1[e] + b1[e])
        gemm1<<<1024, 512, 0, stream>>>(
            xb, W1P, Hs, b1 + (size_t)2 * p * HDIM, wts,
            DDIM, DDIM, KPAIR, DDIM / 64, 32, 16, 2, 2 * p);
        // W2 pair: [2][H][D] -> W2P [D][KPAIR] (after G1: stays L2-hot for G2)
        transpose_cvt_kernel<<<dim3(DDIM / 128, HDIM / 64, 2), 256, 0, stream>>>(
            W2 + (size_t)2 * p * HDIM * DDIM, W2P, HDIM, DDIM, KPAIR,
            (size_t)HDIM * DDIM, HDIM);
        // GEMM2 pair: out += Hs @ W2P^T  (M=8192, N=1024, K=8192; 512 blocks)
        gemm2p<<<512, 256, 0, stream>>>(
            Hs, W2P, out, KPAIR, KPAIR, DDIM, KPAIR / 64, 64, 8, 1);
    }
}

// Round 16
// 1233.209 us; speedup vs baseline: 1.2181x; 1.0235x over previous
//
#include <hip/hip_runtime.h>
#include <hip/hip_bf16.h>

#define DDIM 1024
#define HDIM 4096
#define NEXP 8
#define NROW 8192
#define KPAIR 8192   // 2 experts * HDIM

typedef __attribute__((ext_vector_type(8))) short s16x8;
typedef __attribute__((ext_vector_type(4))) float f32x4;

using bf16 = __hip_bfloat16;

// ---------------------------------------------------------------- helpers
__device__ __forceinline__ void gload16(const bf16* g, bf16* lds) {
    __builtin_amdgcn_global_load_lds(
        (const __attribute__((address_space(1))) unsigned int*)g,
        (__attribute__((address_space(3))) unsigned int*)lds,
        16, 0, 0);
}

template <int N>
__device__ __forceinline__ void wait_vmcnt() {
    if constexpr (N == 6)      asm volatile("s_waitcnt vmcnt(6)" ::: "memory");
    else if constexpr (N == 3) asm volatile("s_waitcnt vmcnt(3)" ::: "memory");
    else                       asm volatile("s_waitcnt vmcnt(0)" ::: "memory");
}

// ---------------------------------------- fused x->bf16 convert + gate softmax
__global__ void cvtgate_kernel(const float* __restrict__ x, const float* __restrict__ Wg,
                               const float* __restrict__ bg, bf16* __restrict__ xb,
                               float* __restrict__ wts) {
    int wave = threadIdx.x >> 6, lane = threadIdx.x & 63;
    int n = blockIdx.x * 4 + wave;
    const float* xr = x + (size_t)n * DDIM;
    bf16* xbr = xb + (size_t)n * DDIM;
    float acc[NEXP] = {0.f, 0.f, 0.f, 0.f, 0.f, 0.f, 0.f, 0.f};
#pragma unroll
    for (int j = 0; j < 4; ++j) {
        int d0 = j * 256 + lane * 4;
        float4 v = *(const float4*)&xr[d0];
        union { bf16 b[4]; uint2 u; } pk;
        pk.b[0] = __float2bfloat16(v.x);
        pk.b[1] = __float2bfloat16(v.y);
        pk.b[2] = __float2bfloat16(v.z);
        pk.b[3] = __float2bfloat16(v.w);
        *(uint2*)&xbr[d0] = pk.u;
        const float* w0 = Wg + (size_t)d0 * NEXP;
#pragma unroll
        for (int e = 0; e < NEXP; ++e)
            acc[e] += v.x * w0[e] + v.y * w0[NEXP + e] + v.z * w0[2 * NEXP + e] +
                      v.w * w0[3 * NEXP + e];
    }
#pragma unroll
    for (int off = 32; off > 0; off >>= 1) {
#pragma unroll
        for (int e = 0; e < NEXP; ++e) acc[e] += __shfl_xor(acc[e], off, 64);
    }
    if (lane == 0) {
        float mx = -1e30f;
#pragma unroll
        for (int e = 0; e < NEXP; ++e) { acc[e] += bg[e]; mx = fmaxf(mx, acc[e]); }
        float s = 0.f;
#pragma unroll
        for (int e = 0; e < NEXP; ++e) { acc[e] = __expf(acc[e] - mx); s += acc[e]; }
        float inv = 1.0f / s;
#pragma unroll
        for (int e = 0; e < NEXP; ++e) wts[(size_t)n * NEXP + e] = acc[e] * inv;
    }
}

// ---------------- merged pair transpose: z<2 -> W1 expert z ([D][H]->[H][D]);
// z>=2 -> W2 expert z-2 ([H][D]-> cols of W2P [D][KPAIR]). One dispatch per
// pair replaces 4 (round-16: fewer launch gaps, overlapping BW ramps).
__global__ void transpose_pair_kernel(const float* __restrict__ W1s, bf16* __restrict__ W1d,
                                      const float* __restrict__ W2s, bf16* __restrict__ W2d) {
    __shared__ float t[128][65];
    const int z = blockIdx.z;
    const float* src; bf16* dst; int C, ldo, bx, by;
    if (z < 2) {
        src = W1s + (size_t)z * DDIM * HDIM;
        dst = W1d + (size_t)z * HDIM * DDIM;
        C = HDIM; ldo = DDIM;
        bx = blockIdx.x & 31; by = blockIdx.x >> 5;    // 32 x 16
    } else {
        src = W2s + (size_t)(z - 2) * HDIM * DDIM;
        dst = W2d + (size_t)(z - 2) * HDIM;
        C = DDIM; ldo = KPAIR;
        bx = blockIdx.x & 7; by = blockIdx.x >> 3;     // 8 x 64
    }
    const int r0 = by * 64, c0 = bx * 128;
    const int tid = threadIdx.x;
    const int lrow = tid >> 5, lc4 = tid & 31;
#pragma unroll
    for (int i = 0; i < 8; ++i) {
        int rr = i * 8 + lrow;
        float4 v = *(const float4*)&src[(size_t)(r0 + rr) * C + c0 + lc4 * 4];
        t[lc4 * 4 + 0][rr] = v.x;
        t[lc4 * 4 + 1][rr] = v.y;
        t[lc4 * 4 + 2][rr] = v.z;
        t[lc4 * 4 + 3][rr] = v.w;
    }
    __syncthreads();
    const int oc = tid >> 3, oj = tid & 7;
#pragma unroll
    for (int i = 0; i < 4; ++i) {
        int c = oc + i * 32;
        union { bf16 b[8]; s16x8 v; } p;
#pragma unroll
        for (int q = 0; q < 8; ++q) p.b[q] = __float2bfloat16(t[c][oj * 8 + q]);
        *(s16x8*)&dst[(size_t)(c0 + c) * ldo + r0 + oj * 8] = p.v;
    }
}

// ------------------------------------------- out[n,d] = sum_e w[n,e]*b2[e,d]
__global__ void out_init_kernel(const float* __restrict__ wts, const float* __restrict__ b2,
                                float* __restrict__ out) {
    size_t idx = (size_t)blockIdx.x * 256 + threadIdx.x;
    int d = (int)(idx & (DDIM - 1));
    size_t n = idx >> 10;
    const float* w = wts + n * NEXP;
    float s = 0.f;
#pragma unroll
    for (int e = 0; e < NEXP; ++e) s += w[e] * b2[(size_t)e * DDIM + d];
    out[idx] = s;
}

// ---------------------------------------------------------------- GEMM1 (8-phase, BK=64)
// BM=256 x BN=256, 8 waves 2(M)x4(N), wave-tile 128x64. PAIR-FUSED dispatch
// (best measured, rounds 11/14/15). Epilogue: Hs = wts[row,e]*relu(acc+b1),
// LDS-buffered coalesced store, granule-XOR swizzle (conflicts 2.1M->0, r14).
__global__ __launch_bounds__(512, 1) void gemm1(
    const bf16* __restrict__ A, const bf16* __restrict__ BTp, bf16* __restrict__ Hsb,
    const float* __restrict__ b1p, const float* __restrict__ wts,
    int lda, int ldb, int ldc, int NT, int tilesM, int tilesN, int XGN, int e0) {
    constexpr int WROWS = 128;
    constexpr int HALFA = 256 * 32;
    constexpr int HALFB = 256 * 32;
    constexpr int ATOT = 2 * HALFA;
    constexpr int BUFE = ATOT + 2 * HALFB;  // 32768 elems
    __shared__ __align__(16) bf16 smem[2 * BUFE];

    const int tid = threadIdx.x;
    const int wave = tid >> 6, lane = tid & 63;
    const int wm = wave >> 2, wn = wave & 3;
    const int r = lane & 15, kg = lane >> 4;

    const int eh = blockIdx.x >> 9;
    const int bx = blockIdx.x & 511;
    const bf16* BT = BTp + (size_t)eh * HDIM * DDIM;
    bf16* Cout = Hsb + (size_t)eh * HDIM;
    const float* bias = b1p + (size_t)eh * HDIM;
    const int expert = e0 + eh;

    // ---- 2-D XCD-aware tile mapping (round-3 FETCH-verified)
    const int xcd = bx & 7, slot = bx >> 3;
    const int XGM = 8 / XGN;
    const int rm = tilesM / XGM, rn = tilesN / XGN;
    const int g = slot >> 5, u = slot & 31;
    const int gpr = rn >> 3;
    const int gm = (g / gpr) * 4 + (u >> 3);
    const int gn = (g % gpr) * 8 + (u & 7);
    const int tm = (xcd / XGN) * rm + gm;
    const int tn = (xcd % XGN) * rn + gn;

    const bf16* gA = A + (size_t)tm * 256 * lda;
    const bf16* gB = BT + (size_t)tn * 256 * ldb;

    f32x4 acc[8][4];
#pragma unroll
    for (int m = 0; m < 8; ++m)
#pragma unroll
        for (int n = 0; n < 4; ++n) acc[m][n] = (f32x4){0.f, 0.f, 0.f, 0.f};

    auto stageA = [&](int t, int ks) {
        bf16* dst = smem + (t & 1) * BUFE + ks * HALFA;
#pragma unroll
        for (int j = 0; j < 2; ++j) {
            int c = j * 512 + tid;
            int R = c >> 2, kc = (c & 3) ^ ((R >> 1) & 3);
            gload16(gA + (size_t)R * lda + t * 64 + ks * 32 + kc * 8,
                    dst + (j * 512 + wave * 64) * 8);
        }
    };
    auto stageB = [&](int t, int ks) {
        bf16* dst = smem + (t & 1) * BUFE + ATOT + ks * HALFB;
#pragma unroll
        for (int j = 0; j < 2; ++j) {
            int c = j * 512 + tid;
            int R = c >> 2, kc = (c & 3) ^ ((R >> 1) & 3);
            gload16(gB + (size_t)R * ldb + t * 64 + ks * 32 + kc * 8,
                    dst + (j * 512 + wave * 64) * 8);
        }
    };

    s16x8 a0[4], bb[4];
    auto ldA = [&](int buf, int ks, int mh) {
#pragma unroll
        for (int m = 0; m < 4; ++m) {
            int R = wm * WROWS + mh * 64 + m * 16 + r;
            a0[m] = *(const s16x8*)&smem[buf * BUFE + ks * HALFA + R * 32 +
                                         ((kg ^ ((R >> 1) & 3)) * 8)];
        }
    };
    auto ldB = [&](int buf, int ks) {
#pragma unroll
        for (int n = 0; n < 4; ++n) {
            int R = wn * 64 + n * 16 + r;
            bb[n] = *(const s16x8*)&smem[buf * BUFE + ATOT + ks * HALFB + R * 32 +
                                         ((kg ^ ((R >> 1) & 3)) * 8)];
        }
    };

    auto preMFMA = [&]() {
        __builtin_amdgcn_s_barrier();
        asm volatile("s_waitcnt lgkmcnt(0)" ::: "memory");
        __builtin_amdgcn_sched_barrier(0);
        __builtin_amdgcn_s_setprio(1);
    };
    auto postMFMA = [&](bool vm) {
        __builtin_amdgcn_s_setprio(0);
        if (vm) wait_vmcnt<6>();
        __builtin_amdgcn_s_barrier();
    };
    auto mfmaLo = [&]() {
#pragma unroll
        for (int m = 0; m < 4; ++m)
#pragma unroll
            for (int n = 0; n < 4; ++n)
                acc[m][n] = __builtin_amdgcn_mfma_f32_16x16x32_bf16(a0[m], bb[n], acc[m][n], 0, 0, 0);
    };
    auto mfmaHi = [&]() {
#pragma unroll
        for (int m = 0; m < 4; ++m)
#pragma unroll
            for (int n = 0; n < 4; ++n)
                acc[4 + m][n] = __builtin_amdgcn_mfma_f32_16x16x32_bf16(a0[m], bb[n], acc[4 + m][n], 0, 0, 0);
    };

    // prologue
    stageB(0, 0); stageA(0, 0); stageB(0, 1); stageA(0, 1);
    stageB(1, 0); stageA(1, 0); stageB(1, 1);   // A(1,1) staged at iter0 ph1
    wait_vmcnt<6>();
    __builtin_amdgcn_s_barrier();

    const int NI = NT / 2;
    for (int i = 0; i < NI; ++i) {
        const int t0 = 2 * i, t1 = t0 + 1;
        const bool g2 = (t0 + 2 < NT), g3 = (t1 + 2 < NT);
        ldB(0, 0); ldA(0, 0, 0); stageA(t1, 1);
        preMFMA(); mfmaLo(); postMFMA(false);
        ldA(0, 0, 1); if (g2) stageB(t0 + 2, 0);
        preMFMA(); mfmaHi(); postMFMA(false);
        ldB(0, 1); ldA(0, 1, 0); if (g2) stageA(t0 + 2, 0);
        preMFMA(); mfmaLo(); postMFMA(false);
        ldA(0, 1, 1); if (g2) stageB(t0 + 2, 1);
        preMFMA(); mfmaHi(); postMFMA(true);
        ldB(1, 0); ldA(1, 0, 0); if (g2) stageA(t0 + 2, 1);
        preMFMA(); mfmaLo(); postMFMA(false);
        ldA(1, 0, 1); if (g3) stageB(t1 + 2, 0);
        preMFMA(); mfmaHi(); postMFMA(false);
        ldB(1, 1); ldA(1, 1, 0); if (g3) stageA(t1 + 2, 0);
        preMFMA(); mfmaLo(); postMFMA(false);
        ldA(1, 1, 1); if (g3) stageB(t1 + 2, 1);
        preMFMA(); mfmaHi(); postMFMA(true);
    }

    // ---- epilogue: Hs = w * relu(acc + bias), LDS-buffered coalesced store.
    bf16* hs = smem;                         // 65536 elems == 256*256
    const int col0 = tn * 256 + wn * 64;
#pragma unroll
    for (int n = 0; n < 4; ++n) {
        float bv = bias[col0 + n * 16 + r];
        int cl = wn * 64 + n * 16 + r;
#pragma unroll
        for (int mf = 0; mf < 8; ++mf) {
#pragma unroll
            for (int j = 0; j < 4; ++j) {
                int rl = wm * WROWS + (mf >> 2) * 64 + (mf & 3) * 16 + kg * 4 + j;
                float wv = wts[((size_t)tm * 256 + rl) * NEXP + expert];
                float v = acc[mf][n][j] + bv;
                v = v > 0.f ? v : 0.f;
                hs[rl * 256 + (cl ^ ((rl & 7) << 3))] = __float2bfloat16(wv * v);
            }
        }
    }
    __builtin_amdgcn_s_barrier();
    asm volatile("s_waitcnt lgkmcnt(0)" ::: "memory");
    const size_t rbase = (size_t)tm * 256;
    const int cbase = tn * 256;
#pragma unroll
    for (int i2 = 0; i2 < 16; ++i2) {
        int rl = wave * 32 + i2 * 2 + (lane >> 5);
        int c8 = (lane & 31) * 8;
        s16x8 v = *(const s16x8*)&hs[rl * 256 + (c8 ^ ((rl & 7) << 3))];
        *(s16x8*)&Cout[(rbase + rl) * (size_t)ldc + cbase + c8] = v;
    }
}

// ---------------------------------------------------------------- GEMM2 v2 (expert-pair, K=8192)
// Round-15 structure (best measured): BM=128 x BN=128, BK=64, 4 waves
// 2(N)x2(Ksw), wave-tile 128x64, dbuf-2 64 KiB -> 2 blocks/CU, grid 512.
__global__ __launch_bounds__(256, 2) void gemm2p(
    const bf16* __restrict__ A, const bf16* __restrict__ BT, float* __restrict__ O,
    int lda, int ldb, int ldc, int NT, int tilesM, int tilesN, int XGN) {
    constexpr int HALFA = 128 * 32;          // 4096 elems (one ks half of A)
    constexpr int HALFB = 128 * 32;
    constexpr int ATOT = 2 * HALFA;
    constexpr int BUFE = ATOT + 2 * HALFB;   // 16384 elems = 32 KiB
    constexpr int RSTR = 68;
    __shared__ __align__(16) bf16 smem[2 * BUFE];   // 64 KiB

    const int tid = threadIdx.x;
    const int wave = tid >> 6, lane = tid & 63;
    const int ksw = wave & 1, wn = wave >> 1;
    const int r = lane & 15, kg = lane >> 4;

    const int xcd = blockIdx.x & 7, slot = blockIdx.x >> 3;
    const int XGM = 8 / XGN;
    const int rm = tilesM / XGM, rn = tilesN / XGN;
    const int g = slot >> 5, u = slot & 31;
    const int gpr = rn >> 3;
    const int gm = (g / gpr) * 4 + (u >> 3);
    const int gn = (g % gpr) * 8 + (u & 7);
    const int tm = (xcd / XGN) * rm + gm;
    const int tn = (xcd % XGN) * rn + gn;

    const bf16* gA = A + (size_t)tm * 128 * lda;
    const bf16* gB = BT + (size_t)tn * 128 * ldb;

    f32x4 acc[8][4];
#pragma unroll
    for (int m = 0; m < 8; ++m)
#pragma unroll
        for (int n = 0; n < 4; ++n) acc[m][n] = (f32x4){0.f, 0.f, 0.f, 0.f};

    auto stageA_rh = [&](int t, int rh) {
        bf16* base = smem + (t & 1) * BUFE;
#pragma unroll
        for (int j = 0; j < 2; ++j) {         // j == ks
            int c = j * 256 + tid;
            int Rl = (c >> 2) & 63;
            int R = rh * 64 + Rl;
            int kc = (c & 3) ^ ((R >> 1) & 3);
            gload16(gA + (size_t)R * lda + t * 64 + j * 32 + kc * 8,
                    base + j * HALFA + rh * 2048 + ((c & 255) - lane) * 8 + lane * 8);
        }
    };
    auto stageB = [&](int t) {
        bf16* base = smem + (t & 1) * BUFE + ATOT;
#pragma unroll
        for (int j = 0; j < 4; ++j) {
            int c = j * 256 + tid;
            int ks = c >> 9;
            int R = (c >> 2) & 127;
            int kc = (c & 3) ^ ((R >> 1) & 3);
            gload16(gB + (size_t)R * ldb + t * 64 + ks * 32 + kc * 8,
                    base + ks * HALFB + ((c & 511) - lane) * 8 + lane * 8);
        }
    };

    s16x8 afr[4], bfr[4];
    auto ldA = [&](int b, int mh) {
#pragma unroll
        for (int m = 0; m < 4; ++m) {
            int R = mh * 64 + m * 16 + r;
            afr[m] = *(const s16x8*)&smem[b * BUFE + ksw * HALFA + R * 32 +
                                          ((kg ^ ((R >> 1) & 3)) * 8)];
        }
    };
    auto ldB = [&](int b) {
#pragma unroll
        for (int n = 0; n < 4; ++n) {
            int R = wn * 64 + n * 16 + r;
            bfr[n] = *(const s16x8*)&smem[b * BUFE + ATOT + ksw * HALFB + R * 32 +
                                          ((kg ^ ((R >> 1) & 3)) * 8)];
        }
    };

    auto preMFMA = [&]() {
        __builtin_amdgcn_s_barrier();
        asm volatile("s_waitcnt lgkmcnt(0)" ::: "memory");
        __builtin_amdgcn_sched_barrier(0);
        __builtin_amdgcn_s_setprio(1);
    };

    // prologue
    stageA_rh(0, 0); stageA_rh(0, 1); stageB(0);
    stageA_rh(1, 1); stageB(1);
    wait_vmcnt<6>();
    __builtin_amdgcn_s_barrier();

    for (int t = 0; t < NT; ++t) {
        const int b = t & 1;
        ldB(b); ldA(b, 1);
        if (t + 1 < NT) stageA_rh(t + 1, 0);
        preMFMA();
#pragma unroll
        for (int m = 0; m < 4; ++m)
#pragma unroll
            for (int n = 0; n < 4; ++n)
                acc[4 + m][n] = __builtin_amdgcn_mfma_f32_16x16x32_bf16(afr[m], bfr[n], acc[4 + m][n], 0, 0, 0);
        __builtin_amdgcn_s_setprio(0);
        __builtin_amdgcn_s_barrier();
        ldA(b, 0);
        if (t + 2 < NT) { stageA_rh(t + 2, 1); stageB(t + 2); }
        preMFMA();
#pragma unroll
        for (int m = 0; m < 4; ++m)
#pragma unroll
            for (int n = 0; n < 4; ++n)
                acc[m][n] = __builtin_amdgcn_mfma_f32_16x16x32_bf16(afr[m], bfr[n], acc[m][n], 0, 0, 0);
        __builtin_amdgcn_s_setprio(0);
        if (t + 1 < NT) {
            if (t + 2 < NT) wait_vmcnt<6>();
            else            wait_vmcnt<0>();
            __builtin_amdgcn_s_barrier();
        }
    }

    // ---- split cross-ksw reduce, two rounds, static acc indices
    __syncthreads();
    float* red = (float*)smem;
    const int zone = wn * (64 * RSTR);
    const int col0 = tn * 128 + wn * 64;
    const size_t row0 = (size_t)tm * 128;
    if (ksw == 1) {
#pragma unroll
        for (int mq = 0; mq < 4; ++mq)
#pragma unroll
            for (int n = 0; n < 4; ++n) {
                int rl = mq * 16 + kg * 4;
                int cl = n * 16 + r;
#pragma unroll
                for (int j = 0; j < 4; ++j)
                    red[zone + (rl + j) * RSTR + cl] = acc[mq][n][j];
            }
    }
    __syncthreads();
    if (ksw == 0) {
#pragma unroll
        for (int mq = 0; mq < 4; ++mq)
#pragma unroll
            for (int j = 0; j < 4; ++j) {
                int rl = mq * 16 + kg * 4 + j;
                size_t rr = row0 + rl;
#pragma unroll
                for (int n = 0; n < 4; ++n) {
                    int cl = n * 16 + r;
                    O[rr * (size_t)ldc + col0 + cl] += acc[mq][n][j] + red[zone + rl * RSTR + cl];
                }
            }
    }
    __syncthreads();
    if (ksw == 0) {
#pragma unroll
        for (int mq = 0; mq < 4; ++mq)
#pragma unroll
            for (int n = 0; n < 4; ++n) {
                int rl = mq * 16 + kg * 4;
                int cl = n * 16 + r;
#pragma unroll
                for (int j = 0; j < 4; ++j)
                    red[zone + (rl + j) * RSTR + cl] = acc[4 + mq][n][j];
            }
    }
    __syncthreads();
    if (ksw == 1) {
#pragma unroll
        for (int mq = 0; mq < 4; ++mq)
#pragma unroll
            for (int j = 0; j < 4; ++j) {
                int rl = mq * 16 + kg * 4 + j;
                size_t rr = row0 + 64 + rl;
#pragma unroll
                for (int n = 0; n < 4; ++n) {
                    int cl = n * 16 + r;
                    O[rr * (size_t)ldc + col0 + cl] += acc[4 + mq][n][j] + red[zone + rl * RSTR + cl];
                }
            }
    }
}

// ---------------------------------------------------------------- launch
extern "C" void kernel_launch(void* const* d_in, const int* in_sizes, int n_in,
                              void* d_out, int out_size, void* d_ws, size_t ws_size,
                              hipStream_t stream) {
    const float* x  = (const float*)d_in[0];
    const float* Wg = (const float*)d_in[1];
    const float* bg = (const float*)d_in[2];
    const float* W1 = (const float*)d_in[3];
    const float* b1 = (const float*)d_in[4];
    const float* W2 = (const float*)d_in[5];
    const float* b2 = (const float*)d_in[6];
    float* out = (float*)d_out;

    char* ws = (char*)d_ws;
    bf16* xb   = (bf16*)(ws);                          // 16 MiB  [N][D]
    bf16* W1P  = (bf16*)(ws + (16ull << 20));          // 16 MiB  [2][H][D] (pair)
    bf16* W2P  = (bf16*)(ws + (32ull << 20));          // 16 MiB  [D][KPAIR] (pair)
    bf16* Hs   = (bf16*)(ws + (48ull << 20));          // 128 MiB [N][KPAIR] (pair)
    float* wts = (float*)(ws + (176ull << 20));        // 256 KiB [N][E]

    cvtgate_kernel<<<NROW / 4, 256, 0, stream>>>(x, Wg, bg, xb, wts);
    out_init_kernel<<<NROW * DDIM / 256, 256, 0, stream>>>(wts, b2, out);

    for (int p = 0; p < 4; ++p) {
        // merged pair transposes: W1 (z=0,1) + W2 (z=2,3) in one dispatch
        transpose_pair_kernel<<<dim3(512, 1, 4), 256, 0, stream>>>(
            W1 + (size_t)2 * p * DDIM * HDIM, W1P,
            W2 + (size_t)2 * p * HDIM * DDIM, W2P);
        // GEMM1 (both experts): Hs[:, eh*H ..] = w * relu(x @ W1[e] + b1[e])
        gemm1<<<1024, 512, 0, stream>>>(
            xb, W1P, Hs, b1 + (size_t)2 * p * HDIM, wts,
            DDIM, DDIM, KPAIR, DDIM / 64, 32, 16, 2, 2 * p);
        // GEMM2 pair: out += Hs @ W2P^T  (M=8192, N=1024, K=8192; 512 blocks)
        gemm2p<<<512, 256, 0, stream>>>(
            Hs, W2P, out, KPAIR, KPAIR, DDIM, KPAIR / 64, 64, 8, 1);
    }
}

// Round 17
// 1228.571 us; speedup vs baseline: 1.2227x; 1.0038x over previous
//
#include <hip/hip_runtime.h>
#include <hip/hip_bf16.h>

#define DDIM 1024
#define HDIM 4096
#define NEXP 8
#define NROW 8192
#define KPAIR 8192   // 2 experts * HDIM

typedef __attribute__((ext_vector_type(8))) short s16x8;
typedef __attribute__((ext_vector_type(4))) float f32x4;

using bf16 = __hip_bfloat16;

// ---------------------------------------------------------------- helpers
__device__ __forceinline__ void gload16(const bf16* g, bf16* lds) {
    __builtin_amdgcn_global_load_lds(
        (const __attribute__((address_space(1))) unsigned int*)g,
        (__attribute__((address_space(3))) unsigned int*)lds,
        16, 0, 0);
}

template <int N>
__device__ __forceinline__ void wait_vmcnt() {
    if constexpr (N == 6)      asm volatile("s_waitcnt vmcnt(6)" ::: "memory");
    else if constexpr (N == 3) asm volatile("s_waitcnt vmcnt(3)" ::: "memory");
    else                       asm volatile("s_waitcnt vmcnt(0)" ::: "memory");
}

// -------- fused x->bf16 convert + gate softmax + out = sum_e w[e]*b2[e,:]
// (round-17: out_init folded in — after the butterfly reduce ALL lanes hold
// the full gate sums, so each wave writes its row's bias-combine directly.)
__global__ void cvtgate_kernel(const float* __restrict__ x, const float* __restrict__ Wg,
                               const float* __restrict__ bg, const float* __restrict__ b2,
                               bf16* __restrict__ xb, float* __restrict__ wts,
                               float* __restrict__ out) {
    int wave = threadIdx.x >> 6, lane = threadIdx.x & 63;
    int n = blockIdx.x * 4 + wave;
    const float* xr = x + (size_t)n * DDIM;
    bf16* xbr = xb + (size_t)n * DDIM;
    float acc[NEXP] = {0.f, 0.f, 0.f, 0.f, 0.f, 0.f, 0.f, 0.f};
#pragma unroll
    for (int j = 0; j < 4; ++j) {
        int d0 = j * 256 + lane * 4;
        float4 v = *(const float4*)&xr[d0];
        union { bf16 b[4]; uint2 u; } pk;
        pk.b[0] = __float2bfloat16(v.x);
        pk.b[1] = __float2bfloat16(v.y);
        pk.b[2] = __float2bfloat16(v.z);
        pk.b[3] = __float2bfloat16(v.w);
        *(uint2*)&xbr[d0] = pk.u;
        const float* w0 = Wg + (size_t)d0 * NEXP;
#pragma unroll
        for (int e = 0; e < NEXP; ++e)
            acc[e] += v.x * w0[e] + v.y * w0[NEXP + e] + v.z * w0[2 * NEXP + e] +
                      v.w * w0[3 * NEXP + e];
    }
#pragma unroll
    for (int off = 32; off > 0; off >>= 1) {
#pragma unroll
        for (int e = 0; e < NEXP; ++e) acc[e] += __shfl_xor(acc[e], off, 64);
    }
    // all lanes now hold the full row sums -> redundant softmax (free)
    float mx = -1e30f;
#pragma unroll
    for (int e = 0; e < NEXP; ++e) { acc[e] += bg[e]; mx = fmaxf(mx, acc[e]); }
    float s = 0.f;
#pragma unroll
    for (int e = 0; e < NEXP; ++e) { acc[e] = __expf(acc[e] - mx); s += acc[e]; }
    float inv = 1.0f / s;
#pragma unroll
    for (int e = 0; e < NEXP; ++e) acc[e] *= inv;
    if (lane == 0) {
#pragma unroll
        for (int e = 0; e < NEXP; ++e) wts[(size_t)n * NEXP + e] = acc[e];
    }
    // out[n, :] = sum_e w[e] * b2[e, :]   (b2 32 KB, L2/L3-hot; float4 I/O)
    float* outr = out + (size_t)n * DDIM;
#pragma unroll
    for (int j = 0; j < 4; ++j) {
        int d0 = j * 256 + lane * 4;
        float4 sum = {0.f, 0.f, 0.f, 0.f};
#pragma unroll
        for (int e = 0; e < NEXP; ++e) {
            float4 bv = *(const float4*)&b2[(size_t)e * DDIM + d0];
            sum.x += acc[e] * bv.x;
            sum.y += acc[e] * bv.y;
            sum.z += acc[e] * bv.z;
            sum.w += acc[e] * bv.w;
        }
        *(float4*)&outr[d0] = sum;
    }
}

// ---------------- merged pair transpose: z<2 -> W1 expert z ([D][H]->[H][D]);
// z>=2 -> W2 expert z-2 ([H][D]-> cols of W2P [D][KPAIR]).
__global__ void transpose_pair_kernel(const float* __restrict__ W1s, bf16* __restrict__ W1d,
                                      const float* __restrict__ W2s, bf16* __restrict__ W2d) {
    __shared__ float t[128][65];
    const int z = blockIdx.z;
    const float* src; bf16* dst; int C, ldo, bx, by;
    if (z < 2) {
        src = W1s + (size_t)z * DDIM * HDIM;
        dst = W1d + (size_t)z * HDIM * DDIM;
        C = HDIM; ldo = DDIM;
        bx = blockIdx.x & 31; by = blockIdx.x >> 5;    // 32 x 16
    } else {
        src = W2s + (size_t)(z - 2) * HDIM * DDIM;
        dst = W2d + (size_t)(z - 2) * HDIM;
        C = DDIM; ldo = KPAIR;
        bx = blockIdx.x & 7; by = blockIdx.x >> 3;     // 8 x 64
    }
    const int r0 = by * 64, c0 = bx * 128;
    const int tid = threadIdx.x;
    const int lrow = tid >> 5, lc4 = tid & 31;
#pragma unroll
    for (int i = 0; i < 8; ++i) {
        int rr = i * 8 + lrow;
        float4 v = *(const float4*)&src[(size_t)(r0 + rr) * C + c0 + lc4 * 4];
        t[lc4 * 4 + 0][rr] = v.x;
        t[lc4 * 4 + 1][rr] = v.y;
        t[lc4 * 4 + 2][rr] = v.z;
        t[lc4 * 4 + 3][rr] = v.w;
    }
    __syncthreads();
    const int oc = tid >> 3, oj = tid & 7;
#pragma unroll
    for (int i = 0; i < 4; ++i) {
        int c = oc + i * 32;
        union { bf16 b[8]; s16x8 v; } p;
#pragma unroll
        for (int q = 0; q < 8; ++q) p.b[q] = __float2bfloat16(t[c][oj * 8 + q]);
        *(s16x8*)&dst[(size_t)(c0 + c) * ldo + r0 + oj * 8] = p.v;
    }
}

// ---------------------------------------------------------------- GEMM1 (8-phase, BK=64)
// BM=256 x BN=256, 8 waves 2(M)x4(N), wave-tile 128x64. PAIR-FUSED dispatch
// (best measured, rounds 11/14/15/16). Epilogue: Hs = wts[row,e]*relu(acc+b1),
// LDS-buffered coalesced store, granule-XOR swizzle (conflicts 2.1M->0, r14).
__global__ __launch_bounds__(512, 1) void gemm1(
    const bf16* __restrict__ A, const bf16* __restrict__ BTp, bf16* __restrict__ Hsb,
    const float* __restrict__ b1p, const float* __restrict__ wts,
    int lda, int ldb, int ldc, int NT, int tilesM, int tilesN, int XGN, int e0) {
    constexpr int WROWS = 128;
    constexpr int HALFA = 256 * 32;
    constexpr int HALFB = 256 * 32;
    constexpr int ATOT = 2 * HALFA;
    constexpr int BUFE = ATOT + 2 * HALFB;  // 32768 elems
    __shared__ __align__(16) bf16 smem[2 * BUFE];

    const int tid = threadIdx.x;
    const int wave = tid >> 6, lane = tid & 63;
    const int wm = wave >> 2, wn = wave & 3;
    const int r = lane & 15, kg = lane >> 4;

    const int eh = blockIdx.x >> 9;
    const int bx = blockIdx.x & 511;
    const bf16* BT = BTp + (size_t)eh * HDIM * DDIM;
    bf16* Cout = Hsb + (size_t)eh * HDIM;
    const float* bias = b1p + (size_t)eh * HDIM;
    const int expert = e0 + eh;

    // ---- 2-D XCD-aware tile mapping (round-3 FETCH-verified)
    const int xcd = bx & 7, slot = bx >> 3;
    const int XGM = 8 / XGN;
    const int rm = tilesM / XGM, rn = tilesN / XGN;
    const int g = slot >> 5, u = slot & 31;
    const int gpr = rn >> 3;
    const int gm = (g / gpr) * 4 + (u >> 3);
    const int gn = (g % gpr) * 8 + (u & 7);
    const int tm = (xcd / XGN) * rm + gm;
    const int tn = (xcd % XGN) * rn + gn;

    const bf16* gA = A + (size_t)tm * 256 * lda;
    const bf16* gB = BT + (size_t)tn * 256 * ldb;

    f32x4 acc[8][4];
#pragma unroll
    for (int m = 0; m < 8; ++m)
#pragma unroll
        for (int n = 0; n < 4; ++n) acc[m][n] = (f32x4){0.f, 0.f, 0.f, 0.f};

    auto stageA = [&](int t, int ks) {
        bf16* dst = smem + (t & 1) * BUFE + ks * HALFA;
#pragma unroll
        for (int j = 0; j < 2; ++j) {
            int c = j * 512 + tid;
            int R = c >> 2, kc = (c & 3) ^ ((R >> 1) & 3);
            gload16(gA + (size_t)R * lda + t * 64 + ks * 32 + kc * 8,
                    dst + (j * 512 + wave * 64) * 8);
        }
    };
    auto stageB = [&](int t, int ks) {
        bf16* dst = smem + (t & 1) * BUFE + ATOT + ks * HALFB;
#pragma unroll
        for (int j = 0; j < 2; ++j) {
            int c = j * 512 + tid;
            int R = c >> 2, kc = (c & 3) ^ ((R >> 1) & 3);
            gload16(gB + (size_t)R * ldb + t * 64 + ks * 32 + kc * 8,
                    dst + (j * 512 + wave * 64) * 8);
        }
    };

    s16x8 a0[4], bb[4];
    auto ldA = [&](int buf, int ks, int mh) {
#pragma unroll
        for (int m = 0; m < 4; ++m) {
            int R = wm * WROWS + mh * 64 + m * 16 + r;
            a0[m] = *(const s16x8*)&smem[buf * BUFE + ks * HALFA + R * 32 +
                                         ((kg ^ ((R >> 1) & 3)) * 8)];
        }
    };
    auto ldB = [&](int buf, int ks) {
#pragma unroll
        for (int n = 0; n < 4; ++n) {
            int R = wn * 64 + n * 16 + r;
            bb[n] = *(const s16x8*)&smem[buf * BUFE + ATOT + ks * HALFB + R * 32 +
                                         ((kg ^ ((R >> 1) & 3)) * 8)];
        }
    };

    auto preMFMA = [&]() {
        __builtin_amdgcn_s_barrier();
        asm volatile("s_waitcnt lgkmcnt(0)" ::: "memory");
        __builtin_amdgcn_sched_barrier(0);
        __builtin_amdgcn_s_setprio(1);
    };
    auto postMFMA = [&](bool vm) {
        __builtin_amdgcn_s_setprio(0);
        if (vm) wait_vmcnt<6>();
        __builtin_amdgcn_s_barrier();
    };
    auto mfmaLo = [&]() {
#pragma unroll
        for (int m = 0; m < 4; ++m)
#pragma unroll
            for (int n = 0; n < 4; ++n)
                acc[m][n] = __builtin_amdgcn_mfma_f32_16x16x32_bf16(a0[m], bb[n], acc[m][n], 0, 0, 0);
    };
    auto mfmaHi = [&]() {
#pragma unroll
        for (int m = 0; m < 4; ++m)
#pragma unroll
            for (int n = 0; n < 4; ++n)
                acc[4 + m][n] = __builtin_amdgcn_mfma_f32_16x16x32_bf16(a0[m], bb[n], acc[4 + m][n], 0, 0, 0);
    };

    // prologue
    stageB(0, 0); stageA(0, 0); stageB(0, 1); stageA(0, 1);
    stageB(1, 0); stageA(1, 0); stageB(1, 1);   // A(1,1) staged at iter0 ph1
    wait_vmcnt<6>();
    __builtin_amdgcn_s_barrier();

    const int NI = NT / 2;
    for (int i = 0; i < NI; ++i) {
        const int t0 = 2 * i, t1 = t0 + 1;
        const bool g2 = (t0 + 2 < NT), g3 = (t1 + 2 < NT);
        ldB(0, 0); ldA(0, 0, 0); stageA(t1, 1);
        preMFMA(); mfmaLo(); postMFMA(false);
        ldA(0, 0, 1); if (g2) stageB(t0 + 2, 0);
        preMFMA(); mfmaHi(); postMFMA(false);
        ldB(0, 1); ldA(0, 1, 0); if (g2) stageA(t0 + 2, 0);
        preMFMA(); mfmaLo(); postMFMA(false);
        ldA(0, 1, 1); if (g2) stageB(t0 + 2, 1);
        preMFMA(); mfmaHi(); postMFMA(true);
        ldB(1, 0); ldA(1, 0, 0); if (g2) stageA(t0 + 2, 1);
        preMFMA(); mfmaLo(); postMFMA(false);
        ldA(1, 0, 1); if (g3) stageB(t1 + 2, 0);
        preMFMA(); mfmaHi(); postMFMA(false);
        ldB(1, 1); ldA(1, 1, 0); if (g3) stageA(t1 + 2, 0);
        preMFMA(); mfmaLo(); postMFMA(false);
        ldA(1, 1, 1); if (g3) stageB(t1 + 2, 1);
        preMFMA(); mfmaHi(); postMFMA(true);
    }

    // ---- epilogue: Hs = w * relu(acc + bias), LDS-buffered coalesced store.
    bf16* hs = smem;                         // 65536 elems == 256*256
    const int col0 = tn * 256 + wn * 64;
#pragma unroll
    for (int n = 0; n < 4; ++n) {
        float bv = bias[col0 + n * 16 + r];
        int cl = wn * 64 + n * 16 + r;
#pragma unroll
        for (int mf = 0; mf < 8; ++mf) {
#pragma unroll
            for (int j = 0; j < 4; ++j) {
                int rl = wm * WROWS + (mf >> 2) * 64 + (mf & 3) * 16 + kg * 4 + j;
                float wv = wts[((size_t)tm * 256 + rl) * NEXP + expert];
                float v = acc[mf][n][j] + bv;
                v = v > 0.f ? v : 0.f;
                hs[rl * 256 + (cl ^ ((rl & 7) << 3))] = __float2bfloat16(wv * v);
            }
        }
    }
    __builtin_amdgcn_s_barrier();
    asm volatile("s_waitcnt lgkmcnt(0)" ::: "memory");
    const size_t rbase = (size_t)tm * 256;
    const int cbase = tn * 256;
#pragma unroll
    for (int i2 = 0; i2 < 16; ++i2) {
        int rl = wave * 32 + i2 * 2 + (lane >> 5);
        int c8 = (lane & 31) * 8;
        s16x8 v = *(const s16x8*)&hs[rl * 256 + (c8 ^ ((rl & 7) << 3))];
        *(s16x8*)&Cout[(rbase + rl) * (size_t)ldc + cbase + c8] = v;
    }
}

// ---------------------------------------------------------------- GEMM2 v2 (expert-pair, K=8192)
// Round-15 structure (best measured): BM=128 x BN=128, BK=64, 4 waves
// 2(N)x2(Ksw), wave-tile 128x64, dbuf-2 64 KiB -> 2 blocks/CU, grid 512.
__global__ __launch_bounds__(256, 2) void gemm2p(
    const bf16* __restrict__ A, const bf16* __restrict__ BT, float* __restrict__ O,
    int lda, int ldb, int ldc, int NT, int tilesM, int tilesN, int XGN) {
    constexpr int HALFA = 128 * 32;          // 4096 elems (one ks half of A)
    constexpr int HALFB = 128 * 32;
    constexpr int ATOT = 2 * HALFA;
    constexpr int BUFE = ATOT + 2 * HALFB;   // 16384 elems = 32 KiB
    constexpr int RSTR = 68;
    __shared__ __align__(16) bf16 smem[2 * BUFE];   // 64 KiB

    const int tid = threadIdx.x;
    const int wave = tid >> 6, lane = tid & 63;
    const int ksw = wave & 1, wn = wave >> 1;
    const int r = lane & 15, kg = lane >> 4;

    const int xcd = blockIdx.x & 7, slot = blockIdx.x >> 3;
    const int XGM = 8 / XGN;
    const int rm = tilesM / XGM, rn = tilesN / XGN;
    const int g = slot >> 5, u = slot & 31;
    const int gpr = rn >> 3;
    const int gm = (g / gpr) * 4 + (u >> 3);
    const int gn = (g % gpr) * 8 + (u & 7);
    const int tm = (xcd / XGN) * rm + gm;
    const int tn = (xcd % XGN) * rn + gn;

    const bf16* gA = A + (size_t)tm * 128 * lda;
    const bf16* gB = BT + (size_t)tn * 128 * ldb;

    f32x4 acc[8][4];
#pragma unroll
    for (int m = 0; m < 8; ++m)
#pragma unroll
        for (int n = 0; n < 4; ++n) acc[m][n] = (f32x4){0.f, 0.f, 0.f, 0.f};

    auto stageA_rh = [&](int t, int rh) {
        bf16* base = smem + (t & 1) * BUFE;
#pragma unroll
        for (int j = 0; j < 2; ++j) {         // j == ks
            int c = j * 256 + tid;
            int Rl = (c >> 2) & 63;
            int R = rh * 64 + Rl;
            int kc = (c & 3) ^ ((R >> 1) & 3);
            gload16(gA + (size_t)R * lda + t * 64 + j * 32 + kc * 8,
                    base + j * HALFA + rh * 2048 + ((c & 255) - lane) * 8 + lane * 8);
        }
    };
    auto stageB = [&](int t) {
        bf16* base = smem + (t & 1) * BUFE + ATOT;
#pragma unroll
        for (int j = 0; j < 4; ++j) {
            int c = j * 256 + tid;
            int ks = c >> 9;
            int R = (c >> 2) & 127;
            int kc = (c & 3) ^ ((R >> 1) & 3);
            gload16(gB + (size_t)R * ldb + t * 64 + ks * 32 + kc * 8,
                    base + ks * HALFB + ((c & 511) - lane) * 8 + lane * 8);
        }
    };

    s16x8 afr[4], bfr[4];
    auto ldA = [&](int b, int mh) {
#pragma unroll
        for (int m = 0; m < 4; ++m) {
            int R = mh * 64 + m * 16 + r;
            afr[m] = *(const s16x8*)&smem[b * BUFE + ksw * HALFA + R * 32 +
                                          ((kg ^ ((R >> 1) & 3)) * 8)];
        }
    };
    auto ldB = [&](int b) {
#pragma unroll
        for (int n = 0; n < 4; ++n) {
            int R = wn * 64 + n * 16 + r;
            bfr[n] = *(const s16x8*)&smem[b * BUFE + ATOT + ksw * HALFB + R * 32 +
                                          ((kg ^ ((R >> 1) & 3)) * 8)];
        }
    };

    auto preMFMA = [&]() {
        __builtin_amdgcn_s_barrier();
        asm volatile("s_waitcnt lgkmcnt(0)" ::: "memory");
        __builtin_amdgcn_sched_barrier(0);
        __builtin_amdgcn_s_setprio(1);
    };

    // prologue
    stageA_rh(0, 0); stageA_rh(0, 1); stageB(0);
    stageA_rh(1, 1); stageB(1);
    wait_vmcnt<6>();
    __builtin_amdgcn_s_barrier();

    for (int t = 0; t < NT; ++t) {
        const int b = t & 1;
        ldB(b); ldA(b, 1);
        if (t + 1 < NT) stageA_rh(t + 1, 0);
        preMFMA();
#pragma unroll
        for (int m = 0; m < 4; ++m)
#pragma unroll
            for (int n = 0; n < 4; ++n)
                acc[4 + m][n] = __builtin_amdgcn_mfma_f32_16x16x32_bf16(afr[m], bfr[n], acc[4 + m][n], 0, 0, 0);
        __builtin_amdgcn_s_setprio(0);
        __builtin_amdgcn_s_barrier();
        ldA(b, 0);
        if (t + 2 < NT) { stageA_rh(t + 2, 1); stageB(t + 2); }
        preMFMA();
#pragma unroll
        for (int m = 0; m < 4; ++m)
#pragma unroll
            for (int n = 0; n < 4; ++n)
                acc[m][n] = __builtin_amdgcn_mfma_f32_16x16x32_bf16(afr[m], bfr[n], acc[m][n], 0, 0, 0);
        __builtin_amdgcn_s_setprio(0);
        if (t + 1 < NT) {
            if (t + 2 < NT) wait_vmcnt<6>();
            else            wait_vmcnt<0>();
            __builtin_amdgcn_s_barrier();
        }
    }

    // ---- split cross-ksw reduce, two rounds, static acc indices
    __syncthreads();
    float* red = (float*)smem;
    const int zone = wn * (64 * RSTR);
    const int col0 = tn * 128 + wn * 64;
    const size_t row0 = (size_t)tm * 128;
    if (ksw == 1) {
#pragma unroll
        for (int mq = 0; mq < 4; ++mq)
#pragma unroll
            for (int n = 0; n < 4; ++n) {
                int rl = mq * 16 + kg * 4;
                int cl = n * 16 + r;
#pragma unroll
                for (int j = 0; j < 4; ++j)
                    red[zone + (rl + j) * RSTR + cl] = acc[mq][n][j];
            }
    }
    __syncthreads();
    if (ksw == 0) {
#pragma unroll
        for (int mq = 0; mq < 4; ++mq)
#pragma unroll
            for (int j = 0; j < 4; ++j) {
                int rl = mq * 16 + kg * 4 + j;
                size_t rr = row0 + rl;
#pragma unroll
                for (int n = 0; n < 4; ++n) {
                    int cl = n * 16 + r;
                    O[rr * (size_t)ldc + col0 + cl] += acc[mq][n][j] + red[zone + rl * RSTR + cl];
                }
            }
    }
    __syncthreads();
    if (ksw == 0) {
#pragma unroll
        for (int mq = 0; mq < 4; ++mq)
#pragma unroll
            for (int n = 0; n < 4; ++n) {
                int rl = mq * 16 + kg * 4;
                int cl = n * 16 + r;
#pragma unroll
                for (int j = 0; j < 4; ++j)
                    red[zone + (rl + j) * RSTR + cl] = acc[4 + mq][n][j];
            }
    }
    __syncthreads();
    if (ksw == 1) {
#pragma unroll
        for (int mq = 0; mq < 4; ++mq)
#pragma unroll
            for (int j = 0; j < 4; ++j) {
                int rl = mq * 16 + kg * 4 + j;
                size_t rr = row0 + 64 + rl;
#pragma unroll
                for (int n = 0; n < 4; ++n) {
                    int cl = n * 16 + r;
                    O[rr * (size_t)ldc + col0 + cl] += acc[4 + mq][n][j] + red[zone + rl * RSTR + cl];
                }
            }
    }
}

// ---------------------------------------------------------------- launch
extern "C" void kernel_launch(void* const* d_in, const int* in_sizes, int n_in,
                              void* d_out, int out_size, void* d_ws, size_t ws_size,
                              hipStream_t stream) {
    const float* x  = (const float*)d_in[0];
    const float* Wg = (const float*)d_in[1];
    const float* bg = (const float*)d_in[2];
    const float* W1 = (const float*)d_in[3];
    const float* b1 = (const float*)d_in[4];
    const float* W2 = (const float*)d_in[5];
    const float* b2 = (const float*)d_in[6];
    float* out = (float*)d_out;

    char* ws = (char*)d_ws;
    bf16* xb   = (bf16*)(ws);                          // 16 MiB  [N][D]
    bf16* W1P  = (bf16*)(ws + (16ull << 20));          // 16 MiB  [2][H][D] (pair)
    bf16* W2P  = (bf16*)(ws + (32ull << 20));          // 16 MiB  [D][KPAIR] (pair)
    bf16* Hs   = (bf16*)(ws + (48ull << 20));          // 128 MiB [N][KPAIR] (pair)
    float* wts = (float*)(ws + (176ull << 20));        // 256 KiB [N][E]

    // fused: x->bf16 + gate softmax + out = sum_e w*b2 (out_init removed)
    cvtgate_kernel<<<NROW / 4, 256, 0, stream>>>(x, Wg, bg, b2, xb, wts, out);

    for (int p = 0; p < 4; ++p) {
        // merged pair transposes: W1 (z=0,1) + W2 (z=2,3) in one dispatch
        transpose_pair_kernel<<<dim3(512, 1, 4), 256, 0, stream>>>(
            W1 + (size_t)2 * p * DDIM * HDIM, W1P,
            W2 + (size_t)2 * p * HDIM * DDIM, W2P);
        // GEMM1 (both experts): Hs[:, eh*H ..] = w * relu(x @ W1[e] + b1[e])
        gemm1<<<1024, 512, 0, stream>>>(
            xb, W1P, Hs, b1 + (size_t)2 * p * HDIM, wts,
            DDIM, DDIM, KPAIR, DDIM / 64, 32, 16, 2, 2 * p);
        // GEMM2 pair: out += Hs @ W2P^T  (M=8192, N=1024, K=8192; 512 blocks)
        gemm2p<<<512, 256, 0, stream>>>(
            Hs, W2P, out, KPAIR, KPAIR, DDIM, KPAIR / 64, 64, 8, 1);
    }
}

// Round 18
// 1221.351 us; speedup vs baseline: 1.2300x; 1.0059x over previous
//
#include <hip/hip_runtime.h>
#include <hip/hip_bf16.h>

#define DDIM 1024
#define HDIM 4096
#define NEXP 8
#define NROW 8192
#define KPAIR 8192   // 2 experts * HDIM

typedef __attribute__((ext_vector_type(8))) short s16x8;
typedef __attribute__((ext_vector_type(4))) float f32x4;

using bf16 = __hip_bfloat16;

// ---------------------------------------------------------------- helpers
__device__ __forceinline__ void gload16(const bf16* g, bf16* lds) {
    __builtin_amdgcn_global_load_lds(
        (const __attribute__((address_space(1))) unsigned int*)g,
        (__attribute__((address_space(3))) unsigned int*)lds,
        16, 0, 0);
}

template <int N>
__device__ __forceinline__ void wait_vmcnt() {
    if constexpr (N == 6)      asm volatile("s_waitcnt vmcnt(6)" ::: "memory");
    else if constexpr (N == 3) asm volatile("s_waitcnt vmcnt(3)" ::: "memory");
    else                       asm volatile("s_waitcnt vmcnt(0)" ::: "memory");
}

// -------- fused x->bf16 convert + gate softmax + out = sum_e w[e]*b2[e,:]
__global__ void cvtgate_kernel(const float* __restrict__ x, const float* __restrict__ Wg,
                               const float* __restrict__ bg, const float* __restrict__ b2,
                               bf16* __restrict__ xb, float* __restrict__ wts,
                               float* __restrict__ out) {
    int wave = threadIdx.x >> 6, lane = threadIdx.x & 63;
    int n = blockIdx.x * 4 + wave;
    const float* xr = x + (size_t)n * DDIM;
    bf16* xbr = xb + (size_t)n * DDIM;
    float acc[NEXP] = {0.f, 0.f, 0.f, 0.f, 0.f, 0.f, 0.f, 0.f};
#pragma unroll
    for (int j = 0; j < 4; ++j) {
        int d0 = j * 256 + lane * 4;
        float4 v = *(const float4*)&xr[d0];
        union { bf16 b[4]; uint2 u; } pk;
        pk.b[0] = __float2bfloat16(v.x);
        pk.b[1] = __float2bfloat16(v.y);
        pk.b[2] = __float2bfloat16(v.z);
        pk.b[3] = __float2bfloat16(v.w);
        *(uint2*)&xbr[d0] = pk.u;
        const float* w0 = Wg + (size_t)d0 * NEXP;
#pragma unroll
        for (int e = 0; e < NEXP; ++e)
            acc[e] += v.x * w0[e] + v.y * w0[NEXP + e] + v.z * w0[2 * NEXP + e] +
                      v.w * w0[3 * NEXP + e];
    }
#pragma unroll
    for (int off = 32; off > 0; off >>= 1) {
#pragma unroll
        for (int e = 0; e < NEXP; ++e) acc[e] += __shfl_xor(acc[e], off, 64);
    }
    float mx = -1e30f;
#pragma unroll
    for (int e = 0; e < NEXP; ++e) { acc[e] += bg[e]; mx = fmaxf(mx, acc[e]); }
    float s = 0.f;
#pragma unroll
    for (int e = 0; e < NEXP; ++e) { acc[e] = __expf(acc[e] - mx); s += acc[e]; }
    float inv = 1.0f / s;
#pragma unroll
    for (int e = 0; e < NEXP; ++e) acc[e] *= inv;
    if (lane == 0) {
#pragma unroll
        for (int e = 0; e < NEXP; ++e) wts[(size_t)n * NEXP + e] = acc[e];
    }
    float* outr = out + (size_t)n * DDIM;
#pragma unroll
    for (int j = 0; j < 4; ++j) {
        int d0 = j * 256 + lane * 4;
        float4 sum = {0.f, 0.f, 0.f, 0.f};
#pragma unroll
        for (int e = 0; e < NEXP; ++e) {
            float4 bv = *(const float4*)&b2[(size_t)e * DDIM + d0];
            sum.x += acc[e] * bv.x;
            sum.y += acc[e] * bv.y;
            sum.z += acc[e] * bv.z;
            sum.w += acc[e] * bv.w;
        }
        *(float4*)&outr[d0] = sum;
    }
}

// ---------------- merged pair transpose: z<2 -> W1 expert z ([D][H]->[H][D]);
// z>=2 -> W2 expert z-2 ([H][D]-> cols of W2P [D][KPAIR]).
__global__ void transpose_pair_kernel(const float* __restrict__ W1s, bf16* __restrict__ W1d,
                                      const float* __restrict__ W2s, bf16* __restrict__ W2d) {
    __shared__ float t[128][65];
    const int z = blockIdx.z;
    const float* src; bf16* dst; int C, ldo, bx, by;
    if (z < 2) {
        src = W1s + (size_t)z * DDIM * HDIM;
        dst = W1d + (size_t)z * HDIM * DDIM;
        C = HDIM; ldo = DDIM;
        bx = blockIdx.x & 31; by = blockIdx.x >> 5;    // 32 x 16
    } else {
        src = W2s + (size_t)(z - 2) * HDIM * DDIM;
        dst = W2d + (size_t)(z - 2) * HDIM;
        C = DDIM; ldo = KPAIR;
        bx = blockIdx.x & 7; by = blockIdx.x >> 3;     // 8 x 64
    }
    const int r0 = by * 64, c0 = bx * 128;
    const int tid = threadIdx.x;
    const int lrow = tid >> 5, lc4 = tid & 31;
#pragma unroll
    for (int i = 0; i < 8; ++i) {
        int rr = i * 8 + lrow;
        float4 v = *(const float4*)&src[(size_t)(r0 + rr) * C + c0 + lc4 * 4];
        t[lc4 * 4 + 0][rr] = v.x;
        t[lc4 * 4 + 1][rr] = v.y;
        t[lc4 * 4 + 2][rr] = v.z;
        t[lc4 * 4 + 3][rr] = v.w;
    }
    __syncthreads();
    const int oc = tid >> 3, oj = tid & 7;
#pragma unroll
    for (int i = 0; i < 4; ++i) {
        int c = oc + i * 32;
        union { bf16 b[8]; s16x8 v; } p;
#pragma unroll
        for (int q = 0; q < 8; ++q) p.b[q] = __float2bfloat16(t[c][oj * 8 + q]);
        *(s16x8*)&dst[(size_t)(c0 + c) * ldo + r0 + oj * 8] = p.v;
    }
}

// ---------------------------------------------------------------- GEMM1 (8-phase, BK=64)
// BM=256 x BN=256, 8 waves 2(M)x4(N), wave-tile 128x64. PAIR-FUSED dispatch
// (best measured). Epilogue: Hs = wts[row,e]*relu(acc+b1), LDS-buffered
// coalesced store, granule-XOR swizzle (conflicts 2.1M->0, r14). Unchanged.
__global__ __launch_bounds__(512, 1) void gemm1(
    const bf16* __restrict__ A, const bf16* __restrict__ BTp, bf16* __restrict__ Hsb,
    const float* __restrict__ b1p, const float* __restrict__ wts,
    int lda, int ldb, int ldc, int NT, int tilesM, int tilesN, int XGN, int e0) {
    constexpr int WROWS = 128;
    constexpr int HALFA = 256 * 32;
    constexpr int HALFB = 256 * 32;
    constexpr int ATOT = 2 * HALFA;
    constexpr int BUFE = ATOT + 2 * HALFB;  // 32768 elems
    __shared__ __align__(16) bf16 smem[2 * BUFE];

    const int tid = threadIdx.x;
    const int wave = tid >> 6, lane = tid & 63;
    const int wm = wave >> 2, wn = wave & 3;
    const int r = lane & 15, kg = lane >> 4;

    const int eh = blockIdx.x >> 9;
    const int bx = blockIdx.x & 511;
    const bf16* BT = BTp + (size_t)eh * HDIM * DDIM;
    bf16* Cout = Hsb + (size_t)eh * HDIM;
    const float* bias = b1p + (size_t)eh * HDIM;
    const int expert = e0 + eh;

    const int xcd = bx & 7, slot = bx >> 3;
    const int XGM = 8 / XGN;
    const int rm = tilesM / XGM, rn = tilesN / XGN;
    const int g = slot >> 5, u = slot & 31;
    const int gpr = rn >> 3;
    const int gm = (g / gpr) * 4 + (u >> 3);
    const int gn = (g % gpr) * 8 + (u & 7);
    const int tm = (xcd / XGN) * rm + gm;
    const int tn = (xcd % XGN) * rn + gn;

    const bf16* gA = A + (size_t)tm * 256 * lda;
    const bf16* gB = BT + (size_t)tn * 256 * ldb;

    f32x4 acc[8][4];
#pragma unroll
    for (int m = 0; m < 8; ++m)
#pragma unroll
        for (int n = 0; n < 4; ++n) acc[m][n] = (f32x4){0.f, 0.f, 0.f, 0.f};

    auto stageA = [&](int t, int ks) {
        bf16* dst = smem + (t & 1) * BUFE + ks * HALFA;
#pragma unroll
        for (int j = 0; j < 2; ++j) {
            int c = j * 512 + tid;
            int R = c >> 2, kc = (c & 3) ^ ((R >> 1) & 3);
            gload16(gA + (size_t)R * lda + t * 64 + ks * 32 + kc * 8,
                    dst + (j * 512 + wave * 64) * 8);
        }
    };
    auto stageB = [&](int t, int ks) {
        bf16* dst = smem + (t & 1) * BUFE + ATOT + ks * HALFB;
#pragma unroll
        for (int j = 0; j < 2; ++j) {
            int c = j * 512 + tid;
            int R = c >> 2, kc = (c & 3) ^ ((R >> 1) & 3);
            gload16(gB + (size_t)R * ldb + t * 64 + ks * 32 + kc * 8,
                    dst + (j * 512 + wave * 64) * 8);
        }
    };

    s16x8 a0[4], bb[4];
    auto ldA = [&](int buf, int ks, int mh) {
#pragma unroll
        for (int m = 0; m < 4; ++m) {
            int R = wm * WROWS + mh * 64 + m * 16 + r;
            a0[m] = *(const s16x8*)&smem[buf * BUFE + ks * HALFA + R * 32 +
                                         ((kg ^ ((R >> 1) & 3)) * 8)];
        }
    };
    auto ldB = [&](int buf, int ks) {
#pragma unroll
        for (int n = 0; n < 4; ++n) {
            int R = wn * 64 + n * 16 + r;
            bb[n] = *(const s16x8*)&smem[buf * BUFE + ATOT + ks * HALFB + R * 32 +
                                         ((kg ^ ((R >> 1) & 3)) * 8)];
        }
    };

    auto preMFMA = [&]() {
        __builtin_amdgcn_s_barrier();
        asm volatile("s_waitcnt lgkmcnt(0)" ::: "memory");
        __builtin_amdgcn_sched_barrier(0);
        __builtin_amdgcn_s_setprio(1);
    };
    auto postMFMA = [&](bool vm) {
        __builtin_amdgcn_s_setprio(0);
        if (vm) wait_vmcnt<6>();
        __builtin_amdgcn_s_barrier();
    };
    auto mfmaLo = [&]() {
#pragma unroll
        for (int m = 0; m < 4; ++m)
#pragma unroll
            for (int n = 0; n < 4; ++n)
                acc[m][n] = __builtin_amdgcn_mfma_f32_16x16x32_bf16(a0[m], bb[n], acc[m][n], 0, 0, 0);
    };
    auto mfmaHi = [&]() {
#pragma unroll
        for (int m = 0; m < 4; ++m)
#pragma unroll
            for (int n = 0; n < 4; ++n)
                acc[4 + m][n] = __builtin_amdgcn_mfma_f32_16x16x32_bf16(a0[m], bb[n], acc[4 + m][n], 0, 0, 0);
    };

    // prologue
    stageB(0, 0); stageA(0, 0); stageB(0, 1); stageA(0, 1);
    stageB(1, 0); stageA(1, 0); stageB(1, 1);   // A(1,1) staged at iter0 ph1
    wait_vmcnt<6>();
    __builtin_amdgcn_s_barrier();

    const int NI = NT / 2;
    for (int i = 0; i < NI; ++i) {
        const int t0 = 2 * i, t1 = t0 + 1;
        const bool g2 = (t0 + 2 < NT), g3 = (t1 + 2 < NT);
        ldB(0, 0); ldA(0, 0, 0); stageA(t1, 1);
        preMFMA(); mfmaLo(); postMFMA(false);
        ldA(0, 0, 1); if (g2) stageB(t0 + 2, 0);
        preMFMA(); mfmaHi(); postMFMA(false);
        ldB(0, 1); ldA(0, 1, 0); if (g2) stageA(t0 + 2, 0);
        preMFMA(); mfmaLo(); postMFMA(false);
        ldA(0, 1, 1); if (g2) stageB(t0 + 2, 1);
        preMFMA(); mfmaHi(); postMFMA(true);
        ldB(1, 0); ldA(1, 0, 0); if (g2) stageA(t0 + 2, 1);
        preMFMA(); mfmaLo(); postMFMA(false);
        ldA(1, 0, 1); if (g3) stageB(t1 + 2, 0);
        preMFMA(); mfmaHi(); postMFMA(false);
        ldB(1, 1); ldA(1, 1, 0); if (g3) stageA(t1 + 2, 0);
        preMFMA(); mfmaLo(); postMFMA(false);
        ldA(1, 1, 1); if (g3) stageB(t1 + 2, 1);
        preMFMA(); mfmaHi(); postMFMA(true);
    }

    // ---- epilogue: Hs = w * relu(acc + bias), LDS-buffered coalesced store.
    bf16* hs = smem;                         // 65536 elems == 256*256
    const int col0 = tn * 256 + wn * 64;
#pragma unroll
    for (int n = 0; n < 4; ++n) {
        float bv = bias[col0 + n * 16 + r];
        int cl = wn * 64 + n * 16 + r;
#pragma unroll
        for (int mf = 0; mf < 8; ++mf) {
#pragma unroll
            for (int j = 0; j < 4; ++j) {
                int rl = wm * WROWS + (mf >> 2) * 64 + (mf & 3) * 16 + kg * 4 + j;
                float wv = wts[((size_t)tm * 256 + rl) * NEXP + expert];
                float v = acc[mf][n][j] + bv;
                v = v > 0.f ? v : 0.f;
                hs[rl * 256 + (cl ^ ((rl & 7) << 3))] = __float2bfloat16(wv * v);
            }
        }
    }
    __builtin_amdgcn_s_barrier();
    asm volatile("s_waitcnt lgkmcnt(0)" ::: "memory");
    const size_t rbase = (size_t)tm * 256;
    const int cbase = tn * 256;
#pragma unroll
    for (int i2 = 0; i2 < 16; ++i2) {
        int rl = wave * 32 + i2 * 2 + (lane >> 5);
        int c8 = (lane & 31) * 8;
        s16x8 v = *(const s16x8*)&hs[rl * 256 + (c8 ^ ((rl & 7) << 3))];
        *(s16x8*)&Cout[(rbase + rl) * (size_t)ldc + cbase + c8] = v;
    }
}

// ---------------------------------------------------------------- GEMM2 v3 (expert-pair, K=8192)
// ROUND-18: ONE barrier per K-tile. dbuf-2, 1-AHEAD prefetch: all of tile
// t+1 staged during tile t into the OTHER buffer (never the active one) ->
// both intra-tile barriers removable. Per tile: {12 ds_reads(t), 8 stages
// (t+1), lgkm(4), 16 MFMA-hi, lgkm(0), 16 MFMA-lo, vmcnt(0), barrier}. The
// full drain is covered by the co-resident partner block (2 blocks/CU, 64
// KiB LDS). WAR: stage(t+1) -> buf(t+1&1), last read in tile t-1, protected
// by end-of-(t-1) barrier. RAW: per-wave vmcnt(0) before end-of-t barrier.
__global__ __launch_bounds__(256, 2) void gemm2p(
    const bf16* __restrict__ A, const bf16* __restrict__ BT, float* __restrict__ O,
    int lda, int ldb, int ldc, int NT, int tilesM, int tilesN, int XGN) {
    constexpr int HALFA = 128 * 32;          // 4096 elems (one ks half of A)
    constexpr int HALFB = 128 * 32;
    constexpr int ATOT = 2 * HALFA;
    constexpr int BUFE = ATOT + 2 * HALFB;   // 16384 elems = 32 KiB
    constexpr int RSTR = 68;
    __shared__ __align__(16) bf16 smem[2 * BUFE];   // 64 KiB

    const int tid = threadIdx.x;
    const int wave = tid >> 6, lane = tid & 63;
    const int ksw = wave & 1, wn = wave >> 1;
    const int r = lane & 15, kg = lane >> 4;

    const int xcd = blockIdx.x & 7, slot = blockIdx.x >> 3;
    const int XGM = 8 / XGN;
    const int rm = tilesM / XGM, rn = tilesN / XGN;
    const int g = slot >> 5, u = slot & 31;
    const int gpr = rn >> 3;
    const int gm = (g / gpr) * 4 + (u >> 3);
    const int gn = (g % gpr) * 8 + (u & 7);
    const int tm = (xcd / XGN) * rm + gm;
    const int tn = (xcd % XGN) * rn + gn;

    const bf16* gA = A + (size_t)tm * 128 * lda;
    const bf16* gB = BT + (size_t)tn * 128 * ldb;

    f32x4 acc[8][4];
#pragma unroll
    for (int m = 0; m < 8; ++m)
#pragma unroll
        for (int n = 0; n < 4; ++n) acc[m][n] = (f32x4){0.f, 0.f, 0.f, 0.f};

    auto stageA_rh = [&](int t, int rh) {
        bf16* base = smem + (t & 1) * BUFE;
#pragma unroll
        for (int j = 0; j < 2; ++j) {         // j == ks
            int c = j * 256 + tid;
            int Rl = (c >> 2) & 63;
            int R = rh * 64 + Rl;
            int kc = (c & 3) ^ ((R >> 1) & 3);
            gload16(gA + (size_t)R * lda + t * 64 + j * 32 + kc * 8,
                    base + j * HALFA + rh * 2048 + ((c & 255) - lane) * 8 + lane * 8);
        }
    };
    auto stageB = [&](int t) {
        bf16* base = smem + (t & 1) * BUFE + ATOT;
#pragma unroll
        for (int j = 0; j < 4; ++j) {
            int c = j * 256 + tid;
            int ks = c >> 9;
            int R = (c >> 2) & 127;
            int kc = (c & 3) ^ ((R >> 1) & 3);
            gload16(gB + (size_t)R * ldb + t * 64 + ks * 32 + kc * 8,
                    base + ks * HALFB + ((c & 511) - lane) * 8 + lane * 8);
        }
    };

    s16x8 a0[4], a1[4], bfr[4];
    auto ldA0 = [&](int b) {
#pragma unroll
        for (int m = 0; m < 4; ++m) {
            int R = m * 16 + r;
            a0[m] = *(const s16x8*)&smem[b * BUFE + ksw * HALFA + R * 32 +
                                         ((kg ^ ((R >> 1) & 3)) * 8)];
        }
    };
    auto ldA1 = [&](int b) {
#pragma unroll
        for (int m = 0; m < 4; ++m) {
            int R = 64 + m * 16 + r;
            a1[m] = *(const s16x8*)&smem[b * BUFE + ksw * HALFA + R * 32 +
                                         ((kg ^ ((R >> 1) & 3)) * 8)];
        }
    };
    auto ldB = [&](int b) {
#pragma unroll
        for (int n = 0; n < 4; ++n) {
            int R = wn * 64 + n * 16 + r;
            bfr[n] = *(const s16x8*)&smem[b * BUFE + ATOT + ksw * HALFB + R * 32 +
                                          ((kg ^ ((R >> 1) & 3)) * 8)];
        }
    };

    // prologue: stage tile 0 only (1-ahead schedule)
    stageA_rh(0, 0); stageA_rh(0, 1); stageB(0);
    wait_vmcnt<0>();
    __builtin_amdgcn_s_barrier();

    for (int t = 0; t < NT; ++t) {
        const int b = t & 1;
        // all 12 reads of tile t: B(4) + A-hi(4) first, A-lo(4) last
        ldB(b); ldA1(b); ldA0(b);
        // stage ALL of t+1 into the other buffer (8 insts)
        if (t + 1 < NT) { stageA_rh(t + 1, 0); stageA_rh(t + 1, 1); stageB(t + 1); }
        // first 8 reads resident (A-lo's 4 ride under MFMA-hi)
        asm volatile("s_waitcnt lgkmcnt(4)" ::: "memory");
        __builtin_amdgcn_sched_barrier(0);
        __builtin_amdgcn_s_setprio(1);
#pragma unroll
        for (int m = 0; m < 4; ++m)
#pragma unroll
            for (int n = 0; n < 4; ++n)
                acc[4 + m][n] = __builtin_amdgcn_mfma_f32_16x16x32_bf16(a1[m], bfr[n], acc[4 + m][n], 0, 0, 0);
        __builtin_amdgcn_s_setprio(0);
        asm volatile("s_waitcnt lgkmcnt(0)" ::: "memory");
        __builtin_amdgcn_sched_barrier(0);
        __builtin_amdgcn_s_setprio(1);
#pragma unroll
        for (int m = 0; m < 4; ++m)
#pragma unroll
            for (int n = 0; n < 4; ++n)
                acc[m][n] = __builtin_amdgcn_mfma_f32_16x16x32_bf16(a0[m], bfr[n], acc[m][n], 0, 0, 0);
        __builtin_amdgcn_s_setprio(0);
        // single tile-boundary sync: drain t+1's stages (partner block covers)
        if (t + 1 < NT) {
            wait_vmcnt<0>();
            __builtin_amdgcn_s_barrier();
        }
    }

    // ---- split cross-ksw reduce, two rounds, static acc indices
    __syncthreads();
    float* red = (float*)smem;
    const int zone = wn * (64 * RSTR);
    const int col0 = tn * 128 + wn * 64;
    const size_t row0 = (size_t)tm * 128;
    if (ksw == 1) {
#pragma unroll
        for (int mq = 0; mq < 4; ++mq)
#pragma unroll
            for (int n = 0; n < 4; ++n) {
                int rl = mq * 16 + kg * 4;
                int cl = n * 16 + r;
#pragma unroll
                for (int j = 0; j < 4; ++j)
                    red[zone + (rl + j) * RSTR + cl] = acc[mq][n][j];
            }
    }
    __syncthreads();
    if (ksw == 0) {
#pragma unroll
        for (int mq = 0; mq < 4; ++mq)
#pragma unroll
            for (int j = 0; j < 4; ++j) {
                int rl = mq * 16 + kg * 4 + j;
                size_t rr = row0 + rl;
#pragma unroll
                for (int n = 0; n < 4; ++n) {
                    int cl = n * 16 + r;
                    O[rr * (size_t)ldc + col0 + cl] += acc[mq][n][j] + red[zone + rl * RSTR + cl];
                }
            }
    }
    __syncthreads();
    if (ksw == 0) {
#pragma unroll
        for (int mq = 0; mq < 4; ++mq)
#pragma unroll
            for (int n = 0; n < 4; ++n) {
                int rl = mq * 16 + kg * 4;
                int cl = n * 16 + r;
#pragma unroll
                for (int j = 0; j < 4; ++j)
                    red[zone + (rl + j) * RSTR + cl] = acc[4 + mq][n][j];
            }
    }
    __syncthreads();
    if (ksw == 1) {
#pragma unroll
        for (int mq = 0; mq < 4; ++mq)
#pragma unroll
            for (int j = 0; j < 4; ++j) {
                int rl = mq * 16 + kg * 4 + j;
                size_t rr = row0 + 64 + rl;
#pragma unroll
                for (int n = 0; n < 4; ++n) {
                    int cl = n * 16 + r;
                    O[rr * (size_t)ldc + col0 + cl] += acc[4 + mq][n][j] + red[zone + rl * RSTR + cl];
                }
            }
    }
}

// ---------------------------------------------------------------- launch
extern "C" void kernel_launch(void* const* d_in, const int* in_sizes, int n_in,
                              void* d_out, int out_size, void* d_ws, size_t ws_size,
                              hipStream_t stream) {
    const float* x  = (const float*)d_in[0];
    const float* Wg = (const float*)d_in[1];
    const float* bg = (const float*)d_in[2];
    const float* W1 = (const float*)d_in[3];
    const float* b1 = (const float*)d_in[4];
    const float* W2 = (const float*)d_in[5];
    const float* b2 = (const float*)d_in[6];
    float* out = (float*)d_out;

    char* ws = (char*)d_ws;
    bf16* xb   = (bf16*)(ws);                          // 16 MiB  [N][D]
    bf16* W1P  = (bf16*)(ws + (16ull << 20));          // 16 MiB  [2][H][D] (pair)
    bf16* W2P  = (bf16*)(ws + (32ull << 20));          // 16 MiB  [D][KPAIR] (pair)
    bf16* Hs   = (bf16*)(ws + (48ull << 20));          // 128 MiB [N][KPAIR] (pair)
    float* wts = (float*)(ws + (176ull << 20));        // 256 KiB [N][E]

    // fused: x->bf16 + gate softmax + out = sum_e w*b2
    cvtgate_kernel<<<NROW / 4, 256, 0, stream>>>(x, Wg, bg, b2, xb, wts, out);

    for (int p = 0; p < 4; ++p) {
        // merged pair transposes: W1 (z=0,1) + W2 (z=2,3) in one dispatch
        transpose_pair_kernel<<<dim3(512, 1, 4), 256, 0, stream>>>(
            W1 + (size_t)2 * p * DDIM * HDIM, W1P,
            W2 + (size_t)2 * p * HDIM * DDIM, W2P);
        // GEMM1 (both experts): Hs[:, eh*H ..] = w * relu(x @ W1[e] + b1[e])
        gemm1<<<1024, 512, 0, stream>>>(
            xb, W1P, Hs, b1 + (size_t)2 * p * HDIM, wts,
            DDIM, DDIM, KPAIR, DDIM / 64, 32, 16, 2, 2 * p);
        // GEMM2 pair: out += Hs @ W2P^T  (M=8192, N=1024, K=8192; 512 blocks)
        gemm2p<<<512, 256, 0, stream>>>(
            Hs, W2P, out, KPAIR, KPAIR, DDIM, KPAIR / 64, 64, 8, 1);
    }
}

// Round 19
// 1220.955 us; speedup vs baseline: 1.2304x; 1.0003x over previous
//
#include <hip/hip_runtime.h>
#include <hip/hip_bf16.h>

#define DDIM 1024
#define HDIM 4096
#define NEXP 8
#define NROW 8192
#define KPAIR 8192   // 2 experts * HDIM

typedef __attribute__((ext_vector_type(8))) short s16x8;
typedef __attribute__((ext_vector_type(4))) float f32x4;

using bf16 = __hip_bfloat16;

// ---------------------------------------------------------------- helpers
__device__ __forceinline__ void gload16(const bf16* g, bf16* lds) {
    __builtin_amdgcn_global_load_lds(
        (const __attribute__((address_space(1))) unsigned int*)g,
        (__attribute__((address_space(3))) unsigned int*)lds,
        16, 0, 0);
}

template <int N>
__device__ __forceinline__ void wait_vmcnt() {
    if constexpr (N == 6)      asm volatile("s_waitcnt vmcnt(6)" ::: "memory");
    else if constexpr (N == 3) asm volatile("s_waitcnt vmcnt(3)" ::: "memory");
    else                       asm volatile("s_waitcnt vmcnt(0)" ::: "memory");
}

// -------- fused x->bf16 convert + gate softmax + out = sum_e w[e]*b2[e,:]
__global__ void cvtgate_kernel(const float* __restrict__ x, const float* __restrict__ Wg,
                               const float* __restrict__ bg, const float* __restrict__ b2,
                               bf16* __restrict__ xb, float* __restrict__ wts,
                               float* __restrict__ out) {
    int wave = threadIdx.x >> 6, lane = threadIdx.x & 63;
    int n = blockIdx.x * 4 + wave;
    const float* xr = x + (size_t)n * DDIM;
    bf16* xbr = xb + (size_t)n * DDIM;
    float acc[NEXP] = {0.f, 0.f, 0.f, 0.f, 0.f, 0.f, 0.f, 0.f};
#pragma unroll
    for (int j = 0; j < 4; ++j) {
        int d0 = j * 256 + lane * 4;
        float4 v = *(const float4*)&xr[d0];
        union { bf16 b[4]; uint2 u; } pk;
        pk.b[0] = __float2bfloat16(v.x);
        pk.b[1] = __float2bfloat16(v.y);
        pk.b[2] = __float2bfloat16(v.z);
        pk.b[3] = __float2bfloat16(v.w);
        *(uint2*)&xbr[d0] = pk.u;
        const float* w0 = Wg + (size_t)d0 * NEXP;
#pragma unroll
        for (int e = 0; e < NEXP; ++e)
            acc[e] += v.x * w0[e] + v.y * w0[NEXP + e] + v.z * w0[2 * NEXP + e] +
                      v.w * w0[3 * NEXP + e];
    }
#pragma unroll
    for (int off = 32; off > 0; off >>= 1) {
#pragma unroll
        for (int e = 0; e < NEXP; ++e) acc[e] += __shfl_xor(acc[e], off, 64);
    }
    float mx = -1e30f;
#pragma unroll
    for (int e = 0; e < NEXP; ++e) { acc[e] += bg[e]; mx = fmaxf(mx, acc[e]); }
    float s = 0.f;
#pragma unroll
    for (int e = 0; e < NEXP; ++e) { acc[e] = __expf(acc[e] - mx); s += acc[e]; }
    float inv = 1.0f / s;
#pragma unroll
    for (int e = 0; e < NEXP; ++e) acc[e] *= inv;
    if (lane == 0) {
#pragma unroll
        for (int e = 0; e < NEXP; ++e) wts[(size_t)n * NEXP + e] = acc[e];
    }
    float* outr = out + (size_t)n * DDIM;
#pragma unroll
    for (int j = 0; j < 4; ++j) {
        int d0 = j * 256 + lane * 4;
        float4 sum = {0.f, 0.f, 0.f, 0.f};
#pragma unroll
        for (int e = 0; e < NEXP; ++e) {
            float4 bv = *(const float4*)&b2[(size_t)e * DDIM + d0];
            sum.x += acc[e] * bv.x;
            sum.y += acc[e] * bv.y;
            sum.z += acc[e] * bv.z;
            sum.w += acc[e] * bv.w;
        }
        *(float4*)&outr[d0] = sum;
    }
}

// ---------------- merged pair transpose: z<2 -> W1 expert z ([D][H]->[H][D]);
// z>=2 -> W2 expert z-2 ([H][D]-> cols of W2P [D][KPAIR]).
__global__ void transpose_pair_kernel(const float* __restrict__ W1s, bf16* __restrict__ W1d,
                                      const float* __restrict__ W2s, bf16* __restrict__ W2d) {
    __shared__ float t[128][65];
    const int z = blockIdx.z;
    const float* src; bf16* dst; int C, ldo, bx, by;
    if (z < 2) {
        src = W1s + (size_t)z * DDIM * HDIM;
        dst = W1d + (size_t)z * HDIM * DDIM;
        C = HDIM; ldo = DDIM;
        bx = blockIdx.x & 31; by = blockIdx.x >> 5;    // 32 x 16
    } else {
        src = W2s + (size_t)(z - 2) * HDIM * DDIM;
        dst = W2d + (size_t)(z - 2) * HDIM;
        C = DDIM; ldo = KPAIR;
        bx = blockIdx.x & 7; by = blockIdx.x >> 3;     // 8 x 64
    }
    const int r0 = by * 64, c0 = bx * 128;
    const int tid = threadIdx.x;
    const int lrow = tid >> 5, lc4 = tid & 31;
#pragma unroll
    for (int i = 0; i < 8; ++i) {
        int rr = i * 8 + lrow;
        float4 v = *(const float4*)&src[(size_t)(r0 + rr) * C + c0 + lc4 * 4];
        t[lc4 * 4 + 0][rr] = v.x;
        t[lc4 * 4 + 1][rr] = v.y;
        t[lc4 * 4 + 2][rr] = v.z;
        t[lc4 * 4 + 3][rr] = v.w;
    }
    __syncthreads();
    const int oc = tid >> 3, oj = tid & 7;
#pragma unroll
    for (int i = 0; i < 4; ++i) {
        int c = oc + i * 32;
        union { bf16 b[8]; s16x8 v; } p;
#pragma unroll
        for (int q = 0; q < 8; ++q) p.b[q] = __float2bfloat16(t[c][oj * 8 + q]);
        *(s16x8*)&dst[(size_t)(c0 + c) * ldo + r0 + oj * 8] = p.v;
    }
}

// ---------------------------------------------------------------- GEMM1 (8-phase, BK=64)
// BM=256 x BN=256, 8 waves 2(M)x4(N), wave-tile 128x64. PAIR-FUSED dispatch.
// ROUND-19: pre-MFMA barrier REMOVED (post-phase barrier alone preserves all
// WAR: each phase's stage targets a region last read >=1 phase earlier, and
// every wave drains its own reads (lgkm 0) before its MFMA, hence before the
// phase-end barrier, hence before any wave's next-phase stage). Waves drift
// within a phase -> MFMA of one wave hides ds_read/stage issue of another
// (the mechanism that paid in G2-v3). Barriers: 16 -> 8 per 2 K-tiles.
__global__ __launch_bounds__(512, 1) void gemm1(
    const bf16* __restrict__ A, const bf16* __restrict__ BTp, bf16* __restrict__ Hsb,
    const float* __restrict__ b1p, const float* __restrict__ wts,
    int lda, int ldb, int ldc, int NT, int tilesM, int tilesN, int XGN, int e0) {
    constexpr int WROWS = 128;
    constexpr int HALFA = 256 * 32;
    constexpr int HALFB = 256 * 32;
    constexpr int ATOT = 2 * HALFA;
    constexpr int BUFE = ATOT + 2 * HALFB;  // 32768 elems
    __shared__ __align__(16) bf16 smem[2 * BUFE];

    const int tid = threadIdx.x;
    const int wave = tid >> 6, lane = tid & 63;
    const int wm = wave >> 2, wn = wave & 3;
    const int r = lane & 15, kg = lane >> 4;

    const int eh = blockIdx.x >> 9;
    const int bx = blockIdx.x & 511;
    const bf16* BT = BTp + (size_t)eh * HDIM * DDIM;
    bf16* Cout = Hsb + (size_t)eh * HDIM;
    const float* bias = b1p + (size_t)eh * HDIM;
    const int expert = e0 + eh;

    const int xcd = bx & 7, slot = bx >> 3;
    const int XGM = 8 / XGN;
    const int rm = tilesM / XGM, rn = tilesN / XGN;
    const int g = slot >> 5, u = slot & 31;
    const int gpr = rn >> 3;
    const int gm = (g / gpr) * 4 + (u >> 3);
    const int gn = (g % gpr) * 8 + (u & 7);
    const int tm = (xcd / XGN) * rm + gm;
    const int tn = (xcd % XGN) * rn + gn;

    const bf16* gA = A + (size_t)tm * 256 * lda;
    const bf16* gB = BT + (size_t)tn * 256 * ldb;

    f32x4 acc[8][4];
#pragma unroll
    for (int m = 0; m < 8; ++m)
#pragma unroll
        for (int n = 0; n < 4; ++n) acc[m][n] = (f32x4){0.f, 0.f, 0.f, 0.f};

    auto stageA = [&](int t, int ks) {
        bf16* dst = smem + (t & 1) * BUFE + ks * HALFA;
#pragma unroll
        for (int j = 0; j < 2; ++j) {
            int c = j * 512 + tid;
            int R = c >> 2, kc = (c & 3) ^ ((R >> 1) & 3);
            gload16(gA + (size_t)R * lda + t * 64 + ks * 32 + kc * 8,
                    dst + (j * 512 + wave * 64) * 8);
        }
    };
    auto stageB = [&](int t, int ks) {
        bf16* dst = smem + (t & 1) * BUFE + ATOT + ks * HALFB;
#pragma unroll
        for (int j = 0; j < 2; ++j) {
            int c = j * 512 + tid;
            int R = c >> 2, kc = (c & 3) ^ ((R >> 1) & 3);
            gload16(gB + (size_t)R * ldb + t * 64 + ks * 32 + kc * 8,
                    dst + (j * 512 + wave * 64) * 8);
        }
    };

    s16x8 a0[4], bb[4];
    auto ldA = [&](int buf, int ks, int mh) {
#pragma unroll
        for (int m = 0; m < 4; ++m) {
            int R = wm * WROWS + mh * 64 + m * 16 + r;
            a0[m] = *(const s16x8*)&smem[buf * BUFE + ks * HALFA + R * 32 +
                                         ((kg ^ ((R >> 1) & 3)) * 8)];
        }
    };
    auto ldB = [&](int buf, int ks) {
#pragma unroll
        for (int n = 0; n < 4; ++n) {
            int R = wn * 64 + n * 16 + r;
            bb[n] = *(const s16x8*)&smem[buf * BUFE + ATOT + ks * HALFB + R * 32 +
                                         ((kg ^ ((R >> 1) & 3)) * 8)];
        }
    };

    // R19: no barrier here — per-wave lgkm drain only, waves drift
    auto preMFMA = [&]() {
        asm volatile("s_waitcnt lgkmcnt(0)" ::: "memory");
        __builtin_amdgcn_sched_barrier(0);
        __builtin_amdgcn_s_setprio(1);
    };
    auto postMFMA = [&](bool vm) {
        __builtin_amdgcn_s_setprio(0);
        if (vm) wait_vmcnt<6>();
        __builtin_amdgcn_s_barrier();
    };
    auto mfmaLo = [&]() {
#pragma unroll
        for (int m = 0; m < 4; ++m)
#pragma unroll
            for (int n = 0; n < 4; ++n)
                acc[m][n] = __builtin_amdgcn_mfma_f32_16x16x32_bf16(a0[m], bb[n], acc[m][n], 0, 0, 0);
    };
    auto mfmaHi = [&]() {
#pragma unroll
        for (int m = 0; m < 4; ++m)
#pragma unroll
            for (int n = 0; n < 4; ++n)
                acc[4 + m][n] = __builtin_amdgcn_mfma_f32_16x16x32_bf16(a0[m], bb[n], acc[4 + m][n], 0, 0, 0);
    };

    // prologue
    stageB(0, 0); stageA(0, 0); stageB(0, 1); stageA(0, 1);
    stageB(1, 0); stageA(1, 0); stageB(1, 1);   // A(1,1) staged at iter0 ph1
    wait_vmcnt<6>();
    __builtin_amdgcn_s_barrier();

    const int NI = NT / 2;
    for (int i = 0; i < NI; ++i) {
        const int t0 = 2 * i, t1 = t0 + 1;
        const bool g2 = (t0 + 2 < NT), g3 = (t1 + 2 < NT);
        ldB(0, 0); ldA(0, 0, 0); stageA(t1, 1);
        preMFMA(); mfmaLo(); postMFMA(false);
        ldA(0, 0, 1); if (g2) stageB(t0 + 2, 0);
        preMFMA(); mfmaHi(); postMFMA(false);
        ldB(0, 1); ldA(0, 1, 0); if (g2) stageA(t0 + 2, 0);
        preMFMA(); mfmaLo(); postMFMA(false);
        ldA(0, 1, 1); if (g2) stageB(t0 + 2, 1);
        preMFMA(); mfmaHi(); postMFMA(true);
        ldB(1, 0); ldA(1, 0, 0); if (g2) stageA(t0 + 2, 1);
        preMFMA(); mfmaLo(); postMFMA(false);
        ldA(1, 0, 1); if (g3) stageB(t1 + 2, 0);
        preMFMA(); mfmaHi(); postMFMA(false);
        ldB(1, 1); ldA(1, 1, 0); if (g3) stageA(t1 + 2, 0);
        preMFMA(); mfmaLo(); postMFMA(false);
        ldA(1, 1, 1); if (g3) stageB(t1 + 2, 1);
        preMFMA(); mfmaHi(); postMFMA(true);
    }

    // ---- epilogue: Hs = w * relu(acc + bias), LDS-buffered coalesced store.
    bf16* hs = smem;                         // 65536 elems == 256*256
    const int col0 = tn * 256 + wn * 64;
#pragma unroll
    for (int n = 0; n < 4; ++n) {
        float bv = bias[col0 + n * 16 + r];
        int cl = wn * 64 + n * 16 + r;
#pragma unroll
        for (int mf = 0; mf < 8; ++mf) {
#pragma unroll
            for (int j = 0; j < 4; ++j) {
                int rl = wm * WROWS + (mf >> 2) * 64 + (mf & 3) * 16 + kg * 4 + j;
                float wv = wts[((size_t)tm * 256 + rl) * NEXP + expert];
                float v = acc[mf][n][j] + bv;
                v = v > 0.f ? v : 0.f;
                hs[rl * 256 + (cl ^ ((rl & 7) << 3))] = __float2bfloat16(wv * v);
            }
        }
    }
    __builtin_amdgcn_s_barrier();
    asm volatile("s_waitcnt lgkmcnt(0)" ::: "memory");
    const size_t rbase = (size_t)tm * 256;
    const int cbase = tn * 256;
#pragma unroll
    for (int i2 = 0; i2 < 16; ++i2) {
        int rl = wave * 32 + i2 * 2 + (lane >> 5);
        int c8 = (lane & 31) * 8;
        s16x8 v = *(const s16x8*)&hs[rl * 256 + (c8 ^ ((rl & 7) << 3))];
        *(s16x8*)&Cout[(rbase + rl) * (size_t)ldc + cbase + c8] = v;
    }
}

// ---------------------------------------------------------------- GEMM2 v3 (expert-pair, K=8192)
// Round-18 structure (best measured): ONE barrier per K-tile, dbuf-2,
// 1-ahead prefetch into the other buffer, 2 blocks/CU partner coverage.
__global__ __launch_bounds__(256, 2) void gemm2p(
    const bf16* __restrict__ A, const bf16* __restrict__ BT, float* __restrict__ O,
    int lda, int ldb, int ldc, int NT, int tilesM, int tilesN, int XGN) {
    constexpr int HALFA = 128 * 32;          // 4096 elems (one ks half of A)
    constexpr int HALFB = 128 * 32;
    constexpr int ATOT = 2 * HALFA;
    constexpr int BUFE = ATOT + 2 * HALFB;   // 16384 elems = 32 KiB
    constexpr int RSTR = 68;
    __shared__ __align__(16) bf16 smem[2 * BUFE];   // 64 KiB

    const int tid = threadIdx.x;
    const int wave = tid >> 6, lane = tid & 63;
    const int ksw = wave & 1, wn = wave >> 1;
    const int r = lane & 15, kg = lane >> 4;

    const int xcd = blockIdx.x & 7, slot = blockIdx.x >> 3;
    const int XGM = 8 / XGN;
    const int rm = tilesM / XGM, rn = tilesN / XGN;
    const int g = slot >> 5, u = slot & 31;
    const int gpr = rn >> 3;
    const int gm = (g / gpr) * 4 + (u >> 3);
    const int gn = (g % gpr) * 8 + (u & 7);
    const int tm = (xcd / XGN) * rm + gm;
    const int tn = (xcd % XGN) * rn + gn;

    const bf16* gA = A + (size_t)tm * 128 * lda;
    const bf16* gB = BT + (size_t)tn * 128 * ldb;

    f32x4 acc[8][4];
#pragma unroll
    for (int m = 0; m < 8; ++m)
#pragma unroll
        for (int n = 0; n < 4; ++n) acc[m][n] = (f32x4){0.f, 0.f, 0.f, 0.f};

    auto stageA_rh = [&](int t, int rh) {
        bf16* base = smem + (t & 1) * BUFE;
#pragma unroll
        for (int j = 0; j < 2; ++j) {         // j == ks
            int c = j * 256 + tid;
            int Rl = (c >> 2) & 63;
            int R = rh * 64 + Rl;
            int kc = (c & 3) ^ ((R >> 1) & 3);
            gload16(gA + (size_t)R * lda + t * 64 + j * 32 + kc * 8,
                    base + j * HALFA + rh * 2048 + ((c & 255) - lane) * 8 + lane * 8);
        }
    };
    auto stageB = [&](int t) {
        bf16* base = smem + (t & 1) * BUFE + ATOT;
#pragma unroll
        for (int j = 0; j < 4; ++j) {
            int c = j * 256 + tid;
            int ks = c >> 9;
            int R = (c >> 2) & 127;
            int kc = (c & 3) ^ ((R >> 1) & 3);
            gload16(gB + (size_t)R * ldb + t * 64 + ks * 32 + kc * 8,
                    base + ks * HALFB + ((c & 511) - lane) * 8 + lane * 8);
        }
    };

    s16x8 a0[4], a1[4], bfr[4];
    auto ldA0 = [&](int b) {
#pragma unroll
        for (int m = 0; m < 4; ++m) {
            int R = m * 16 + r;
            a0[m] = *(const s16x8*)&smem[b * BUFE + ksw * HALFA + R * 32 +
                                         ((kg ^ ((R >> 1) & 3)) * 8)];
        }
    };
    auto ldA1 = [&](int b) {
#pragma unroll
        for (int m = 0; m < 4; ++m) {
            int R = 64 + m * 16 + r;
            a1[m] = *(const s16x8*)&smem[b * BUFE + ksw * HALFA + R * 32 +
                                         ((kg ^ ((R >> 1) & 3)) * 8)];
        }
    };
    auto ldB = [&](int b) {
#pragma unroll
        for (int n = 0; n < 4; ++n) {
            int R = wn * 64 + n * 16 + r;
            bfr[n] = *(const s16x8*)&smem[b * BUFE + ATOT + ksw * HALFB + R * 32 +
                                          ((kg ^ ((R >> 1) & 3)) * 8)];
        }
    };

    // prologue: stage tile 0 only (1-ahead schedule)
    stageA_rh(0, 0); stageA_rh(0, 1); stageB(0);
    wait_vmcnt<0>();
    __builtin_amdgcn_s_barrier();

    for (int t = 0; t < NT; ++t) {
        const int b = t & 1;
        ldB(b); ldA1(b); ldA0(b);
        if (t + 1 < NT) { stageA_rh(t + 1, 0); stageA_rh(t + 1, 1); stageB(t + 1); }
        asm volatile("s_waitcnt lgkmcnt(4)" ::: "memory");
        __builtin_amdgcn_sched_barrier(0);
        __builtin_amdgcn_s_setprio(1);
#pragma unroll
        for (int m = 0; m < 4; ++m)
#pragma unroll
            for (int n = 0; n < 4; ++n)
                acc[4 + m][n] = __builtin_amdgcn_mfma_f32_16x16x32_bf16(a1[m], bfr[n], acc[4 + m][n], 0, 0, 0);
        __builtin_amdgcn_s_setprio(0);
        asm volatile("s_waitcnt lgkmcnt(0)" ::: "memory");
        __builtin_amdgcn_sched_barrier(0);
        __builtin_amdgcn_s_setprio(1);
#pragma unroll
        for (int m = 0; m < 4; ++m)
#pragma unroll
            for (int n = 0; n < 4; ++n)
                acc[m][n] = __builtin_amdgcn_mfma_f32_16x16x32_bf16(a0[m], bfr[n], acc[m][n], 0, 0, 0);
        __builtin_amdgcn_s_setprio(0);
        if (t + 1 < NT) {
            wait_vmcnt<0>();
            __builtin_amdgcn_s_barrier();
        }
    }

    // ---- split cross-ksw reduce, two rounds, static acc indices
    __syncthreads();
    float* red = (float*)smem;
    const int zone = wn * (64 * RSTR);
    const int col0 = tn * 128 + wn * 64;
    const size_t row0 = (size_t)tm * 128;
    if (ksw == 1) {
#pragma unroll
        for (int mq = 0; mq < 4; ++mq)
#pragma unroll
            for (int n = 0; n < 4; ++n) {
                int rl = mq * 16 + kg * 4;
                int cl = n * 16 + r;
#pragma unroll
                for (int j = 0; j < 4; ++j)
                    red[zone + (rl + j) * RSTR + cl] = acc[mq][n][j];
            }
    }
    __syncthreads();
    if (ksw == 0) {
#pragma unroll
        for (int mq = 0; mq < 4; ++mq)
#pragma unroll
            for (int j = 0; j < 4; ++j) {
                int rl = mq * 16 + kg * 4 + j;
                size_t rr = row0 + rl;
#pragma unroll
                for (int n = 0; n < 4; ++n) {
                    int cl = n * 16 + r;
                    O[rr * (size_t)ldc + col0 + cl] += acc[mq][n][j] + red[zone + rl * RSTR + cl];
                }
            }
    }
    __syncthreads();
    if (ksw == 0) {
#pragma unroll
        for (int mq = 0; mq < 4; ++mq)
#pragma unroll
            for (int n = 0; n < 4; ++n) {
                int rl = mq * 16 + kg * 4;
                int cl = n * 16 + r;
#pragma unroll
                for (int j = 0; j < 4; ++j)
                    red[zone + (rl + j) * RSTR + cl] = acc[4 + mq][n][j];
            }
    }
    __syncthreads();
    if (ksw == 1) {
#pragma unroll
        for (int mq = 0; mq < 4; ++mq)
#pragma unroll
            for (int j = 0; j < 4; ++j) {
                int rl = mq * 16 + kg * 4 + j;
                size_t rr = row0 + 64 + rl;
#pragma unroll
                for (int n = 0; n < 4; ++n) {
                    int cl = n * 16 + r;
                    O[rr * (size_t)ldc + col0 + cl] += acc[4 + mq][n][j] + red[zone + rl * RSTR + cl];
                }
            }
    }
}

// ---------------------------------------------------------------- launch
extern "C" void kernel_launch(void* const* d_in, const int* in_sizes, int n_in,
                              void* d_out, int out_size, void* d_ws, size_t ws_size,
                              hipStream_t stream) {
    const float* x  = (const float*)d_in[0];
    const float* Wg = (const float*)d_in[1];
    const float* bg = (const float*)d_in[2];
    const float* W1 = (const float*)d_in[3];
    const float* b1 = (const float*)d_in[4];
    const float* W2 = (const float*)d_in[5];
    const float* b2 = (const float*)d_in[6];
    float* out = (float*)d_out;

    char* ws = (char*)d_ws;
    bf16* xb   = (bf16*)(ws);                          // 16 MiB  [N][D]
    bf16* W1P  = (bf16*)(ws + (16ull << 20));          // 16 MiB  [2][H][D] (pair)
    bf16* W2P  = (bf16*)(ws + (32ull << 20));          // 16 MiB  [D][KPAIR] (pair)
    bf16* Hs   = (bf16*)(ws + (48ull << 20));          // 128 MiB [N][KPAIR] (pair)
    float* wts = (float*)(ws + (176ull << 20));        // 256 KiB [N][E]

    // fused: x->bf16 + gate softmax + out = sum_e w*b2
    cvtgate_kernel<<<NROW / 4, 256, 0, stream>>>(x, Wg, bg, b2, xb, wts, out);

    for (int p = 0; p < 4; ++p) {
        // merged pair transposes: W1 (z=0,1) + W2 (z=2,3) in one dispatch
        transpose_pair_kernel<<<dim3(512, 1, 4), 256, 0, stream>>>(
            W1 + (size_t)2 * p * DDIM * HDIM, W1P,
            W2 + (size_t)2 * p * HDIM * DDIM, W2P);
        // GEMM1 (both experts): Hs[:, eh*H ..] = w * relu(x @ W1[e] + b1[e])
        gemm1<<<1024, 512, 0, stream>>>(
            xb, W1P, Hs, b1 + (size_t)2 * p * HDIM, wts,
            DDIM, DDIM, KPAIR, DDIM / 64, 32, 16, 2, 2 * p);
        // GEMM2 pair: out += Hs @ W2P^T  (M=8192, N=1024, K=8192; 512 blocks)
        gemm2p<<<512, 256, 0, stream>>>(
            Hs, W2P, out, KPAIR, KPAIR, DDIM, KPAIR / 64, 64, 8, 1);
    }
}